// Round 7
// baseline (685.793 us; speedup 1.0000x reference)
//
#include <hip/hip_runtime.h>
#include <hip/hip_bf16.h>

#define N_NODES 100000
#define E_EDGES 800000
#define E2 (E_EDGES + N_NODES)   // 900000 edges incl. self loops
#define FIN 128
#define HD 64
#define NH 8
#define NG 128
#define NC 10
#define SLOPE 0.2f
#define SELF_FLAG 0x40000000
#define SRC_MASK  0x3FFFFFFF
#define NSCAN_BLK 391            // ceil(N/256)
#define NBLK64 1563              // ceil(N/64)

typedef unsigned short bfu;

__device__ __forceinline__ float lrelu(float x) { return x > 0.f ? x : SLOPE * x; }

__device__ __forceinline__ bfu f2bf(float f) {
    unsigned int u = __float_as_uint(f);
    u += 0x7FFFu + ((u >> 16) & 1u);          // round-to-nearest-even
    return (bfu)(u >> 16);
}
__device__ __forceinline__ float bf2f(bfu s) {
    return __uint_as_float(((unsigned int)s) << 16);
}
__device__ __forceinline__ float bflo(unsigned int u) { return __uint_as_float(u << 16); }
__device__ __forceinline__ float bfhi(unsigned int u) { return __uint_as_float(u & 0xFFFF0000u); }

// ---------------------------------------------------------------------------
// Tiled node GEMM: 64 nodes/block, thread = 4 nodes x 4 outputs.
// Output table in bf16 (for gather consumers). MODE 1: es/ed head-dot epilogue.
// ---------------------------------------------------------------------------
template<int KIN, int MODE>
__global__ __launch_bounds__(256)
void gemm_tile(const float* __restrict__ in, const float* __restrict__ W,
               bfu* __restrict__ outB,
               const float* __restrict__ a_s, const float* __restrict__ a_d,
               float* __restrict__ es, float* __restrict__ ed)
{
    __shared__ float Ws[KIN * 64];
    __shared__ float rows[64 * (KIN + 1)];
    int t = threadIdx.x;
    int base = blockIdx.x * 64;
    {
        const float4* Wv = (const float4*)W;
        float4* Wsv = (float4*)Ws;
        for (int i = t; i < KIN * 16; i += 256) Wsv[i] = Wv[i];
    }
    constexpr int RQ = KIN / 4;
    for (int i = t; i < 64 * RQ; i += 256) {
        int r = i / RQ, c = (i % RQ) * 4;
        int n = base + r;
        float4 v = make_float4(0.f, 0.f, 0.f, 0.f);
        if (n < N_NODES) v = *(const float4*)(in + (size_t)n * KIN + c);
        float* dp = rows + r * (KIN + 1) + c;
        dp[0] = v.x; dp[1] = v.y; dp[2] = v.z; dp[3] = v.w;
    }
    __syncthreads();
    int tr = t >> 4, tc = t & 15;
    float acc[4][4] = {};
    const float4* Wsv = (const float4*)Ws;
#pragma unroll 8
    for (int k = 0; k < KIN; ++k) {
        float4 w = Wsv[k * 16 + tc];
        float rv[4];
#pragma unroll
        for (int i = 0; i < 4; ++i) rv[i] = rows[(tr * 4 + i) * (KIN + 1) + k];
#pragma unroll
        for (int i = 0; i < 4; ++i) {
            acc[i][0] = fmaf(rv[i], w.x, acc[i][0]);
            acc[i][1] = fmaf(rv[i], w.y, acc[i][1]);
            acc[i][2] = fmaf(rv[i], w.z, acc[i][2]);
            acc[i][3] = fmaf(rv[i], w.w, acc[i][3]);
        }
    }
    int j0 = tc * 4;
#pragma unroll
    for (int i = 0; i < 4; ++i) {
        int n = base + tr * 4 + i;
        if (n < N_NODES) {
            ushort4 ov;
            ov.x = f2bf(acc[i][0]); ov.y = f2bf(acc[i][1]);
            ov.z = f2bf(acc[i][2]); ov.w = f2bf(acc[i][3]);
            *(ushort4*)(outB + (size_t)n * 64 + j0) = ov;
        }
    }
    if (MODE == 1) {
        float s0[4], s1[4];
#pragma unroll
        for (int i = 0; i < 4; ++i) {
            float pes = 0.f, ped = 0.f;
#pragma unroll
            for (int q = 0; q < 4; ++q) {
                pes = fmaf(acc[i][q], a_s[j0 + q], pes);
                ped = fmaf(acc[i][q], a_d[j0 + q], ped);
            }
            pes += __shfl_xor(pes, 1, 64);
            ped += __shfl_xor(ped, 1, 64);
            s0[i] = pes; s1[i] = ped;
        }
        if ((tc & 1) == 0) {
            int h = tc >> 1;
#pragma unroll
            for (int i = 0; i < 4; ++i) {
                int n = base + tr * 4 + i;
                if (n < N_NODES) {
                    es[n * NH + h] = s0[i];
                    ed[n * NH + h] = s1[i];
                }
            }
        }
    }
}

// ---------------------------------------------------------------------------
// Dual node GEMM (shared fp32 input, two weight mats, bf16 outputs).
// SCALED: out_i *= sc_i[n].
// ---------------------------------------------------------------------------
template<int SCALED>
__global__ __launch_bounds__(256)
void gemm_dual(const float* __restrict__ in, const float* __restrict__ W0,
               const float* __restrict__ W1,
               const float* __restrict__ sc0, const float* __restrict__ sc1,
               bfu* __restrict__ out0, bfu* __restrict__ out1)
{
    __shared__ float Ws[2 * 64 * 64];
    __shared__ float rows[64 * 65];
    int t = threadIdx.x;
    int base = blockIdx.x * 64;
    {
        const float4* W0v = (const float4*)W0;
        const float4* W1v = (const float4*)W1;
        float4* Wsv = (float4*)Ws;
        for (int i = t; i < 1024; i += 256) { Wsv[i] = W0v[i]; Wsv[1024 + i] = W1v[i]; }
    }
    for (int i = t; i < 64 * 16; i += 256) {
        int r = i / 16, c = (i % 16) * 4;
        int n = base + r;
        float4 v = make_float4(0.f, 0.f, 0.f, 0.f);
        if (n < N_NODES) v = *(const float4*)(in + (size_t)n * 64 + c);
        float* dp = rows + r * 65 + c;
        dp[0] = v.x; dp[1] = v.y; dp[2] = v.z; dp[3] = v.w;
    }
    __syncthreads();
    int tr = t >> 4, tc = t & 15;
    float a0[4][4] = {}, a1[4][4] = {};
    const float4* Wsv = (const float4*)Ws;
#pragma unroll 4
    for (int k = 0; k < 64; ++k) {
        float4 w0 = Wsv[k * 16 + tc];
        float4 w1 = Wsv[1024 + k * 16 + tc];
        float rv[4];
#pragma unroll
        for (int i = 0; i < 4; ++i) rv[i] = rows[(tr * 4 + i) * 65 + k];
#pragma unroll
        for (int i = 0; i < 4; ++i) {
            a0[i][0] = fmaf(rv[i], w0.x, a0[i][0]);
            a0[i][1] = fmaf(rv[i], w0.y, a0[i][1]);
            a0[i][2] = fmaf(rv[i], w0.z, a0[i][2]);
            a0[i][3] = fmaf(rv[i], w0.w, a0[i][3]);
            a1[i][0] = fmaf(rv[i], w1.x, a1[i][0]);
            a1[i][1] = fmaf(rv[i], w1.y, a1[i][1]);
            a1[i][2] = fmaf(rv[i], w1.z, a1[i][2]);
            a1[i][3] = fmaf(rv[i], w1.w, a1[i][3]);
        }
    }
    int j0 = tc * 4;
#pragma unroll
    for (int i = 0; i < 4; ++i) {
        int n = base + tr * 4 + i;
        if (n >= N_NODES) continue;
        float m0 = 1.f, m1 = 1.f;
        if (SCALED) { m0 = sc0[n]; m1 = sc1[n]; }
        ushort4 o0, o1;
        o0.x = f2bf(a0[i][0] * m0); o0.y = f2bf(a0[i][1] * m0);
        o0.z = f2bf(a0[i][2] * m0); o0.w = f2bf(a0[i][3] * m0);
        o1.x = f2bf(a1[i][0] * m1); o1.y = f2bf(a1[i][1] * m1);
        o1.z = f2bf(a1[i][2] * m1); o1.w = f2bf(a1[i][3] * m1);
        *(ushort4*)(out0 + (size_t)n * 64 + j0) = o0;
        *(ushort4*)(out1 + (size_t)n * 64 + j0) = o1;
    }
}

// ---------------------------------------------------------------------------
// CSR build: histogram -> scan -> scatter (+ dst array)
// ---------------------------------------------------------------------------
__global__ void csr_hist(const int* __restrict__ ei, int* __restrict__ cnt)
{
    int e = blockIdx.x * 256 + threadIdx.x;
    if (e >= E_EDGES) return;
    atomicAdd(&cnt[ei[E_EDGES + e]], 1);
}

__global__ void csr_scan1(const int* __restrict__ cnt, int* __restrict__ offs,
                          int* __restrict__ bsum)
{
    __shared__ int tmp[256];
    int t = threadIdx.x;
    int i = blockIdx.x * 256 + t;
    int v = (i < N_NODES) ? cnt[i] + 1 : 0;
    tmp[t] = v; __syncthreads();
#pragma unroll
    for (int o = 1; o < 256; o <<= 1) {
        int a = (t >= o) ? tmp[t - o] : 0;
        __syncthreads();
        tmp[t] += a;
        __syncthreads();
    }
    if (i < N_NODES) offs[i] = tmp[t] - v;
    if (t == 255) bsum[blockIdx.x] = tmp[255];
}

__global__ void csr_scan2(int* __restrict__ bsum)
{
    __shared__ int tmp[512];
    int t = threadIdx.x;
    int v = (t < NSCAN_BLK) ? bsum[t] : 0;
    tmp[t] = v; __syncthreads();
#pragma unroll
    for (int o = 1; o < 512; o <<= 1) {
        int a = (t >= o) ? tmp[t - o] : 0;
        __syncthreads();
        tmp[t] += a;
        __syncthreads();
    }
    if (t < NSCAN_BLK) bsum[t] = tmp[t] - v;
}

__global__ void csr_scan3(int* __restrict__ offs, const int* __restrict__ bsum,
                          int* __restrict__ cursor)
{
    int i = blockIdx.x * 256 + threadIdx.x;
    if (i < N_NODES) {
        int v = offs[i] + bsum[blockIdx.x];
        offs[i] = v;
        cursor[i] = v;
    }
    if (i == 0) offs[N_NODES] = E2;
}

__global__ void csr_scatter(const int* __restrict__ ei, int* __restrict__ cursor,
                            int* __restrict__ csr, int* __restrict__ csrd)
{
    int e = blockIdx.x * 256 + threadIdx.x;
    if (e >= E2) return;
    int d, tag;
    if (e < E_EDGES) { int s = ei[e]; d = ei[E_EDGES + e]; tag = s; }
    else             { d = e - E_EDGES; tag = d | SELF_FLAG; }
    int pos = atomicAdd(&cursor[d], 1);
    csr[pos] = tag;
    csrd[pos] = d;
}

// ---------------------------------------------------------------------------
// Fused GAT aggregate: wave per dst node; 4 edge-slots x 16 feature-lanes.
// Single pass (no segment-max; logits O(1)). bf16 gather, fp32 accumulate.
// ---------------------------------------------------------------------------
template<int ELU>
__global__ void gat_aggregate4(const int* __restrict__ offs, const int* __restrict__ csr,
                               const float* __restrict__ es, const float* __restrict__ ed,
                               const bfu* __restrict__ hsrcB, const float* __restrict__ bias,
                               float* __restrict__ out)
{
    int n = blockIdx.x * 4 + (threadIdx.x >> 6);
    int lane = threadIdx.x & 63;
    if (n >= N_NODES) return;
    int g  = lane >> 4;        // edge slot 0..3
    int fl = lane & 15;        // feature chunk: features fl*4 .. fl*4+3
    int h  = fl >> 1;          // head
    int beg = offs[n], end = offs[n + 1];
    float edv = ed[n * NH + h];
    float den = 0.f;
    float4 acc = make_float4(0.f, 0.f, 0.f, 0.f);
    for (int p = beg + g; p < end; p += 4) {
        int s = csr[p] & SRC_MASK;
        float l = lrelu(es[s * NH + h] + edv);
        float ex = __expf(l);
        den += ex;
        ushort4 rb = *(const ushort4*)(hsrcB + (size_t)s * HD + fl * 4);
        acc.x = fmaf(bf2f(rb.x), ex, acc.x);
        acc.y = fmaf(bf2f(rb.y), ex, acc.y);
        acc.z = fmaf(bf2f(rb.z), ex, acc.z);
        acc.w = fmaf(bf2f(rb.w), ex, acc.w);
    }
#pragma unroll
    for (int o = 16; o <= 32; o <<= 1) {
        den   += __shfl_xor(den,   o, 64);
        acc.x += __shfl_xor(acc.x, o, 64);
        acc.y += __shfl_xor(acc.y, o, 64);
        acc.z += __shfl_xor(acc.z, o, 64);
        acc.w += __shfl_xor(acc.w, o, 64);
    }
    if (g == 0) {
        float inv = 1.f / (den + 1e-16f);
        float4 bv = *(const float4*)(bias + fl * 4);
        float v0 = acc.x * inv + bv.x;
        float v1 = acc.y * inv + bv.y;
        float v2 = acc.z * inv + bv.z;
        float v3 = acc.w * inv + bv.w;
        if (ELU) {
            v0 = v0 > 0.f ? v0 : (__expf(v0) - 1.f);
            v1 = v1 > 0.f ? v1 : (__expf(v1) - 1.f);
            v2 = v2 > 0.f ? v2 : (__expf(v2) - 1.f);
            v3 = v3 > 0.f ? v3 : (__expf(v3) - 1.f);
        }
        *(float4*)(out + (size_t)n * HD + fl * 4) = make_float4(v0, v1, v2, v3);
    }
}

// ---------------------------------------------------------------------------
// node attention, tiled: 64 nodes/block, w1+rows staged in LDS.
// ---------------------------------------------------------------------------
__global__ __launch_bounds__(256)
void node_att_tile(const float* __restrict__ H, const float* __restrict__ w1,
                   const float* __restrict__ b1, const float* __restrict__ w2,
                   const float* __restrict__ b2, float* __restrict__ ac,
                   float* __restrict__ at)
{
    __shared__ float w1s[64 * 32];
    __shared__ float w2s[64];
    __shared__ float rows[64 * 65];
    int t = threadIdx.x;
    int base = blockIdx.x * 64;
    {
        const float4* w1v = (const float4*)w1;
        float4* dst = (float4*)w1s;
        for (int i = t; i < 512; i += 256) dst[i] = w1v[i];
    }
    if (t < 64) w2s[t] = w2[t];
    for (int i = t; i < 64 * 16; i += 256) {
        int r = i >> 4, c = (i & 15) * 4;
        int n = base + r;
        float4 v = make_float4(0.f, 0.f, 0.f, 0.f);
        if (n < N_NODES) v = *(const float4*)(H + (size_t)n * 64 + c);
        float* dp = rows + r * 65 + c;
        dp[0] = v.x; dp[1] = v.y; dp[2] = v.z; dp[3] = v.w;
    }
    __syncthreads();
    int tr = t >> 3;
    int tc = t & 7;
    float4 bv = *(const float4*)(b1 + tc * 4);
    float4 acc0 = bv, acc1 = bv;
    const float4* w1sv = (const float4*)w1s;
#pragma unroll 8
    for (int k = 0; k < 64; ++k) {
        float4 w = w1sv[k * 8 + tc];
        float r0 = rows[tr * 65 + k];
        float r1 = rows[(tr + 32) * 65 + k];
        acc0.x = fmaf(r0, w.x, acc0.x); acc0.y = fmaf(r0, w.y, acc0.y);
        acc0.z = fmaf(r0, w.z, acc0.z); acc0.w = fmaf(r0, w.w, acc0.w);
        acc1.x = fmaf(r1, w.x, acc1.x); acc1.y = fmaf(r1, w.y, acc1.y);
        acc1.z = fmaf(r1, w.z, acc1.z); acc1.w = fmaf(r1, w.w, acc1.w);
    }
    float z00 = 0.f, z01 = 0.f, z10 = 0.f, z11 = 0.f;
    float h0, w20, w21;
    int j0 = tc * 4;
#pragma unroll
    for (int q = 0; q < 4; ++q) {
        float a0q = q == 0 ? acc0.x : q == 1 ? acc0.y : q == 2 ? acc0.z : acc0.w;
        float a1q = q == 0 ? acc1.x : q == 1 ? acc1.y : q == 2 ? acc1.z : acc1.w;
        w20 = w2s[(j0 + q) * 2]; w21 = w2s[(j0 + q) * 2 + 1];
        h0 = fmaxf(a0q, 0.f);
        z00 = fmaf(h0, w20, z00); z01 = fmaf(h0, w21, z01);
        h0 = fmaxf(a1q, 0.f);
        z10 = fmaf(h0, w20, z10); z11 = fmaf(h0, w21, z11);
    }
#pragma unroll
    for (int o = 1; o < 8; o <<= 1) {
        z00 += __shfl_xor(z00, o, 64); z01 += __shfl_xor(z01, o, 64);
        z10 += __shfl_xor(z10, o, 64); z11 += __shfl_xor(z11, o, 64);
    }
    if (tc == 0) {
        int n0 = base + tr, n1 = base + tr + 32;
        if (n0 < N_NODES) {
            float zz0 = z00 + b2[0], zz1 = z01 + b2[1];
            float mx = fmaxf(zz0, zz1);
            float e0 = __expf(zz0 - mx), e1 = __expf(zz1 - mx);
            float ss = e0 + e1;
            ac[n0] = e0 / ss; at[n0] = e1 / ss;
        }
        if (n1 < N_NODES) {
            float zz0 = z10 + b2[0], zz1 = z11 + b2[1];
            float mx = fmaxf(zz0, zz1);
            float e0 = __expf(zz0 - mx), e1 = __expf(zz1 - mx);
            float ss = e0 + e1;
            ac[n1] = e0 / ss; at[n1] = e1 / ss;
        }
    }
}

// ---------------------------------------------------------------------------
// edge attention, flat over CSR: 8 lanes/edge, bf16 P1/P2 gather.
// Also accumulates beta sums into degc/degt (GCN degree) via atomics.
// ---------------------------------------------------------------------------
__global__ __launch_bounds__(256)
void edge_att_flat(const int* __restrict__ csr, const int* __restrict__ csrd,
                   const bfu* __restrict__ P1b, const bfu* __restrict__ P2b,
                   const float* __restrict__ b1, const float* __restrict__ w2,
                   const float* __restrict__ b2,
                   float* __restrict__ bc, float* __restrict__ bt,
                   float* __restrict__ degc, float* __restrict__ degt)
{
    int lane = threadIdx.x & 63;
    int sg = lane >> 3, q = lane & 7;
    int p = (blockIdx.x * 4 + (threadIdx.x >> 6)) * 8 + sg;
    if (p >= E2) return;
    int sv = csr[p];
    if (sv & SELF_FLAG) return;
    int d = csrd[p];
    uint4 U1 = *(const uint4*)(P1b + (size_t)sv * 64 + q * 8);
    uint4 U2 = *(const uint4*)(P2b + (size_t)d  * 64 + q * 8);
    const float4* pb = (const float4*)(b1 + q * 8);
    const float4* pw = (const float4*)(w2 + q * 16);
    float4 c0 = pb[0], c1 = pb[1];
    float4 w0 = pw[0], w1v = pw[1], w2v = pw[2], w3v = pw[3];
    float h0 = fmaxf(bflo(U1.x) + bflo(U2.x) + c0.x, 0.f);
    float h1 = fmaxf(bfhi(U1.x) + bfhi(U2.x) + c0.y, 0.f);
    float h2 = fmaxf(bflo(U1.y) + bflo(U2.y) + c0.z, 0.f);
    float h3 = fmaxf(bfhi(U1.y) + bfhi(U2.y) + c0.w, 0.f);
    float h4 = fmaxf(bflo(U1.z) + bflo(U2.z) + c1.x, 0.f);
    float h5 = fmaxf(bfhi(U1.z) + bfhi(U2.z) + c1.y, 0.f);
    float h6 = fmaxf(bflo(U1.w) + bflo(U2.w) + c1.z, 0.f);
    float h7 = fmaxf(bfhi(U1.w) + bfhi(U2.w) + c1.w, 0.f);
    float z0 = h0 * w0.x + h1 * w0.z + h2 * w1v.x + h3 * w1v.z
             + h4 * w2v.x + h5 * w2v.z + h6 * w3v.x + h7 * w3v.z;
    float z1 = h0 * w0.y + h1 * w0.w + h2 * w1v.y + h3 * w1v.w
             + h4 * w2v.y + h5 * w2v.w + h6 * w3v.y + h7 * w3v.w;
    z0 += __shfl_xor(z0, 1, 64); z1 += __shfl_xor(z1, 1, 64);
    z0 += __shfl_xor(z0, 2, 64); z1 += __shfl_xor(z1, 2, 64);
    z0 += __shfl_xor(z0, 4, 64); z1 += __shfl_xor(z1, 4, 64);
    if (q == 0) {
        z0 += b2[0]; z1 += b2[1];
        float mx = fmaxf(z0, z1);
        float e0 = __expf(z0 - mx), e1 = __expf(z1 - mx);
        float ss = e0 + e1;
        float vc = e0 / ss, vt = e1 / ss;
        bc[p] = vc;
        bt[p] = vt;
        atomicAdd(&degc[d], vc);
        atomicAdd(&degt[d], vt);
    }
}

// deg -> dis: rsqrt(deg + 1)   (+1 = the self loop; always > 0)
__global__ void deg_to_dis(float* __restrict__ degc, float* __restrict__ degt)
{
    int n = blockIdx.x * 256 + threadIdx.x;
    if (n >= N_NODES) return;
    degc[n] = rsqrtf(degc[n] + 1.f);
    degt[n] = rsqrtf(degt[n] + 1.f);
}

__global__ void gcn_norm(const int* __restrict__ csr, const int* __restrict__ csrd,
                         const float* __restrict__ disc, const float* __restrict__ dist,
                         float* __restrict__ bc, float* __restrict__ bt)
{
    int p = blockIdx.x * 256 + threadIdx.x;
    if (p >= E2) return;
    int sv = csr[p];
    int s = sv & SRC_MASK;
    int d = csrd[p];
    float wc, wt;
    if (sv & SELF_FLAG) { wc = 1.f; wt = 1.f; }
    else { wc = bc[p]; wt = bt[p]; }
    bc[p] = disc[s] * wc * disc[d];
    bt[p] = dist[s] * wt * dist[d];
}

__global__ void gcn_aggregate_both(const int* __restrict__ offs, const int* __restrict__ csr,
                                   const bfu* __restrict__ preC, const bfu* __restrict__ preT,
                                   const float* __restrict__ nrmC, const float* __restrict__ nrmT,
                                   float* __restrict__ outC, float* __restrict__ outT)
{
    int n = blockIdx.x * 4 + (threadIdx.x >> 6);
    int lane = threadIdx.x & 63;
    if (n >= N_NODES) return;
    int g  = lane >> 4;
    int fl = lane & 15;
    int beg = offs[n], end = offs[n + 1];
    float4 a1 = make_float4(0.f, 0.f, 0.f, 0.f);
    float4 a2 = make_float4(0.f, 0.f, 0.f, 0.f);
    for (int p = beg + g; p < end; p += 4) {
        int s = csr[p] & SRC_MASK;
        float wc = nrmC[p], wt = nrmT[p];
        ushort4 rc = *(const ushort4*)(preC + (size_t)s * HD + fl * 4);
        ushort4 rt = *(const ushort4*)(preT + (size_t)s * HD + fl * 4);
        a1.x = fmaf(bf2f(rc.x), wc, a1.x);
        a1.y = fmaf(bf2f(rc.y), wc, a1.y);
        a1.z = fmaf(bf2f(rc.z), wc, a1.z);
        a1.w = fmaf(bf2f(rc.w), wc, a1.w);
        a2.x = fmaf(bf2f(rt.x), wt, a2.x);
        a2.y = fmaf(bf2f(rt.y), wt, a2.y);
        a2.z = fmaf(bf2f(rt.z), wt, a2.z);
        a2.w = fmaf(bf2f(rt.w), wt, a2.w);
    }
#pragma unroll
    for (int o = 16; o <= 32; o <<= 1) {
        a1.x += __shfl_xor(a1.x, o, 64); a1.y += __shfl_xor(a1.y, o, 64);
        a1.z += __shfl_xor(a1.z, o, 64); a1.w += __shfl_xor(a1.w, o, 64);
        a2.x += __shfl_xor(a2.x, o, 64); a2.y += __shfl_xor(a2.y, o, 64);
        a2.z += __shfl_xor(a2.z, o, 64); a2.w += __shfl_xor(a2.w, o, 64);
    }
    if (g == 0) {
        *(float4*)(outC + (size_t)n * HD + fl * 4) = a1;
        *(float4*)(outT + (size_t)n * HD + fl * 4) = a2;
    }
}

// ---------------------------------------------------------------------------
// readout (both branches): wave per 8 consecutive nodes (high occupancy)
// ---------------------------------------------------------------------------
#define RO_CHUNK 8
__global__ void readout_both(const float* __restrict__ Gc, const float* __restrict__ Gt,
                             const int* __restrict__ batch,
                             float* __restrict__ S_c, float* __restrict__ S_t,
                             float* __restrict__ cnt)
{
    int chunk = blockIdx.x * 4 + (threadIdx.x >> 6);
    int lane = threadIdx.x & 63;
    int n0 = chunk * RO_CHUNK;
    if (n0 >= N_NODES) return;
    int n1 = n0 + RO_CHUNK; if (n1 > N_NODES) n1 = N_NODES;
    int gp = batch[n0];
    float a1 = 0.f, a2 = 0.f; int rc = 0;
    for (int n = n0; n < n1; ++n) {
        int g = batch[n];
        if (g != gp) {
            atomicAdd(&S_c[gp * 64 + lane], a1);
            atomicAdd(&S_t[gp * 64 + lane], a2);
            if (lane == 0) atomicAdd(&cnt[gp], (float)rc);
            a1 = a2 = 0.f; rc = 0; gp = g;
        }
        a1 += Gc[(size_t)n * 64 + lane];
        a2 += Gt[(size_t)n * 64 + lane];
        ++rc;
    }
    atomicAdd(&S_c[gp * 64 + lane], a1);
    atomicAdd(&S_t[gp * 64 + lane], a2);
    if (lane == 0) atomicAdd(&cnt[gp], (float)rc);
}

// ---------------------------------------------------------------------------
// final per-graph heads
// ---------------------------------------------------------------------------
__global__ void final_head(const float* __restrict__ S_c, const float* __restrict__ S_t,
                           const float* __restrict__ cnt,
                           const float* __restrict__ gc_b, const float* __restrict__ gt_b,
                           const float* __restrict__ rc_w, const float* __restrict__ rc_b,
                           const float* __restrict__ rt_w, const float* __restrict__ rt_b,
                           const float* __restrict__ cc_w1, const float* __restrict__ cc_b1,
                           const float* __restrict__ cc_w2, const float* __restrict__ cc_b2,
                           const float* __restrict__ ct_w1, const float* __restrict__ ct_b1,
                           const float* __restrict__ ct_w2, const float* __restrict__ ct_b2,
                           const float* __restrict__ cm_w1, const float* __restrict__ cm_b1,
                           const float* __restrict__ cm_w2, const float* __restrict__ cm_b2,
                           float* __restrict__ out)
{
    int g = blockIdx.x;
    int j = threadIdx.x;
    __shared__ float sc[64], st[64], hgc[64], hgt[64], hid[64];
    float c = cnt[g];
    sc[j] = S_c[g * 64 + j] + c * gc_b[j];
    st[j] = S_t[g * 64 + j] + c * gt_b[j];
    __syncthreads();
    float acr = c * rc_b[j], atr = c * rt_b[j];
#pragma unroll 8
    for (int k = 0; k < 64; ++k) {
        acr = fmaf(sc[k], rc_w[k * 64 + j], acr);
        atr = fmaf(st[k], rt_w[k * 64 + j], atr);
    }
    hgc[j] = acr; hgt[j] = atr;
    out[3840 + g * 64 + j]  = acr;
    out[12032 + g * 64 + j] = atr;
    __syncthreads();
    float hv = 0.f;
    if (j < 32) {
        float a = cc_b1[j];
#pragma unroll 8
        for (int k = 0; k < 64; ++k) a = fmaf(hgc[k], cc_w1[k * 32 + j], a);
        hv = fmaxf(a, 0.f);
    }
    hid[j] = hv;
    __syncthreads();
    if (j < NC) {
        float a = cc_b2[j];
#pragma unroll
        for (int k = 0; k < 32; ++k) a = fmaf(hid[k], cc_w2[k * NC + j], a);
        out[g * NC + j] = a;
    }
    __syncthreads();
    hv = 0.f;
    if (j < 32) {
        float a = ct_b1[j];
#pragma unroll 8
        for (int k = 0; k < 64; ++k) a = fmaf(hgt[k], ct_w1[k * 32 + j], a);
        hv = fmaxf(a, 0.f);
    }
    hid[j] = hv;
    __syncthreads();
    if (j < NC) {
        float a = ct_b2[j];
#pragma unroll
        for (int k = 0; k < 32; ++k) a = fmaf(hid[k], ct_w2[k * NC + j], a);
        out[1280 + g * NC + j] = a;
    }
    __syncthreads();
    {
        float a = cm_b1[j];
#pragma unroll 8
        for (int k = 0; k < 64; ++k) {
            a = fmaf(hgc[k], cm_w1[k * 64 + j], a);
            a = fmaf(hgt[k], cm_w1[(64 + k) * 64 + j], a);
        }
        hid[j] = fmaxf(a, 0.f);
    }
    __syncthreads();
    if (j < NC) {
        float a = cm_b2[j];
#pragma unroll 8
        for (int k = 0; k < 64; ++k) a = fmaf(hid[k], cm_w2[k * NC + j], a);
        out[2560 + g * NC + j] = a;
    }
}

// ---------------------------------------------------------------------------
extern "C" void kernel_launch(void* const* d_in, const int* in_sizes, int n_in,
                              void* d_out, int out_size, void* d_ws, size_t ws_size,
                              hipStream_t stream)
{
    const float* x     = (const float*)d_in[0];
    const int*   ei    = (const int*)d_in[1];
    const int*   batch = (const int*)d_in[2];
    const float* W1    = (const float*)d_in[3];
    const float* as1   = (const float*)d_in[4];
    const float* ad1   = (const float*)d_in[5];
    const float* b1    = (const float*)d_in[6];
    const float* W2    = (const float*)d_in[7];
    const float* as2   = (const float*)d_in[8];
    const float* ad2   = (const float*)d_in[9];
    const float* b2    = (const float*)d_in[10];
    const float* na_w1 = (const float*)d_in[11];
    const float* na_b1 = (const float*)d_in[12];
    const float* na_w2 = (const float*)d_in[13];
    const float* na_b2 = (const float*)d_in[14];
    const float* ea_w1 = (const float*)d_in[15];
    const float* ea_b1 = (const float*)d_in[16];
    const float* ea_w2 = (const float*)d_in[17];
    const float* ea_b2 = (const float*)d_in[18];
    const float* gc_w  = (const float*)d_in[19];
    const float* gc_b  = (const float*)d_in[20];
    const float* gt_w  = (const float*)d_in[21];
    const float* gt_b  = (const float*)d_in[22];
    const float* rc_w  = (const float*)d_in[23];
    const float* rc_b  = (const float*)d_in[24];
    const float* rt_w  = (const float*)d_in[25];
    const float* rt_b  = (const float*)d_in[26];
    const float* cc_w1 = (const float*)d_in[27];
    const float* cc_b1 = (const float*)d_in[28];
    const float* cc_w2 = (const float*)d_in[29];
    const float* cc_b2 = (const float*)d_in[30];
    const float* ct_w1 = (const float*)d_in[31];
    const float* ct_b1 = (const float*)d_in[32];
    const float* ct_w2 = (const float*)d_in[33];
    const float* ct_b2 = (const float*)d_in[34];
    const float* cm_w1 = (const float*)d_in[35];
    const float* cm_b1 = (const float*)d_in[36];
    const float* cm_w2 = (const float*)d_in[37];
    const float* cm_b2 = (const float*)d_in[38];
    float* out = (float*)d_out;

    float* ws = (float*)d_ws;
    size_t o = 0;
    const size_t nf = (size_t)N_NODES * HD;
    float* T1   = ws + o; o += nf;             // H1 / Gc-agg out
    float* T2   = ws + o; o += nf;             // H  / Gt-agg out
    float* es   = ws + o; o += (size_t)N_NODES * NH;
    float* ed   = ws + o; o += (size_t)N_NODES * NH;
    float* ac   = ws + o; o += N_NODES;
    float* at   = ws + o; o += N_NODES;
    float* bc   = ws + o; o += E2;             // beta_c -> norm_c (in place)
    float* bt   = ws + o; o += E2;             // beta_t -> norm_t (in place)
    float* degc = ws + o; o += N_NODES;        // deg sums -> dis (in place)
    float* degt = ws + o; o += N_NODES;
    float* S_c  = ws + o; o += NG * 64;
    float* S_t  = ws + o; o += NG * 64;
    float* cntf = ws + o; o += NG;
    bfu* B0     = (bfu*)(ws + o); o += nf / 2; // bf16 gather table
    bfu* B1     = (bfu*)(ws + o); o += nf / 2; // bf16 gather table
    int* csr    = (int*)(ws + o); o += E2;
    int* csrd   = (int*)(ws + o); o += E2;
    int* offs   = (int*)(ws + o); o += N_NODES + 1;
    int* cnt    = (int*)at;
    int* cursor = (int*)ac;
    int* bsum   = (int*)degc;   // consumed before degc memset

    const int NW_BLKS = N_NODES / 4;             // 25000
    const int NT_BLKS = (N_NODES + 255) / 256;   // 391
    const int E_BLKS  = (E2 + 255) / 256;        // 3516
    const int EF_BLKS = (E2 + 31) / 32;          // 28125
    const int RO_BLKS = (N_NODES / RO_CHUNK) / 4;  // 3125

    // ---------------- CSR build ----------------
    hipMemsetAsync(cnt, 0, (size_t)N_NODES * 4, stream);
    csr_hist<<<(E_EDGES + 255) / 256, 256, 0, stream>>>(ei, cnt);
    csr_scan1<<<NSCAN_BLK, 256, 0, stream>>>(cnt, offs, bsum);
    csr_scan2<<<1, 512, 0, stream>>>(bsum);
    csr_scan3<<<NSCAN_BLK, 256, 0, stream>>>(offs, bsum, cursor);
    csr_scatter<<<E_BLKS, 256, 0, stream>>>(ei, cursor, csr, csrd);

    // ---------------- GAT layer 1 ----------------
    gemm_tile<FIN, 1><<<NBLK64, 256, 0, stream>>>(x, W1, B0, as1, ad1, es, ed);
    gat_aggregate4<1><<<NW_BLKS, 256, 0, stream>>>(offs, csr, es, ed, B0, b1, T1);

    // ---------------- GAT layer 2 ----------------
    gemm_tile<64, 1><<<NBLK64, 256, 0, stream>>>(T1, W2, B0, as2, ad2, es, ed);
    gat_aggregate4<0><<<NW_BLKS, 256, 0, stream>>>(offs, csr, es, ed, B0, b2, T2);

    // ---------------- node attention ----------------
    node_att_tile<<<NBLK64, 256, 0, stream>>>(T2, na_w1, na_b1, na_w2, na_b2, ac, at);

    // ---------------- edge attention (P1 -> B0, P2 -> B1, bf16) -------------
    // (also accumulates GCN degree sums into degc/degt)
    hipMemsetAsync(degc, 0, (size_t)2 * N_NODES * 4, stream);
    gemm_dual<0><<<NBLK64, 256, 0, stream>>>(T2, ea_w1, ea_w1 + 64 * 64,
                                             nullptr, nullptr, B0, B1);
    edge_att_flat<<<EF_BLKS, 256, 0, stream>>>(csr, csrd, B0, B1, ea_b1, ea_w2, ea_b2,
                                               bc, bt, degc, degt);

    // ---------------- GCN norm (bc/bt -> per-edge norms in place) -----------
    deg_to_dis<<<NT_BLKS, 256, 0, stream>>>(degc, degt);
    gcn_norm<<<E_BLKS, 256, 0, stream>>>(csr, csrd, degc, degt, bc, bt);

    hipMemsetAsync(S_c, 0, (size_t)(2 * NG * 64 + NG) * 4, stream);

    // ---------------- GCN pre-transforms (pre_c -> B0, pre_t -> B1) ---------
    gemm_dual<1><<<NBLK64, 256, 0, stream>>>(T2, gc_w, gt_w, ac, at, B0, B1);

    // ---------------- GCN aggregate (both) + readout ------------------------
    gcn_aggregate_both<<<NW_BLKS, 256, 0, stream>>>(offs, csr, B0, B1, bc, bt, T1, T2);
    readout_both<<<RO_BLKS, 256, 0, stream>>>(T1, T2, batch, S_c, S_t, cntf);

    // ---------------- heads ----------------
    final_head<<<NG, 64, 0, stream>>>(S_c, S_t, cntf,
                                      gc_b, gt_b, rc_w, rc_b, rt_w, rt_b,
                                      cc_w1, cc_b1, cc_w2, cc_b2,
                                      ct_w1, ct_b1, ct_w2, ct_b2,
                                      cm_w1, cm_b1, cm_w2, cm_b2, out);
    (void)in_sizes; (void)n_in; (void)out_size; (void)ws_size;
}

// Round 8
// 655.602 us; speedup vs baseline: 1.0461x; 1.0461x over previous
//
#include <hip/hip_runtime.h>
#include <hip/hip_bf16.h>

#define N_NODES 100000
#define E_EDGES 800000
#define E2 (E_EDGES + N_NODES)   // 900000 edges incl. self loops
#define FIN 128
#define HD 64
#define NH 8
#define NG 128
#define NC 10
#define SLOPE 0.2f
#define SELF_FLAG 0x40000000
#define SRC_MASK  0x3FFFFFFF
#define NSCAN_BLK 391            // ceil(N/256)
#define NBLK64 1563              // ceil(N/64)

typedef unsigned short bfu;

__device__ __forceinline__ float lrelu(float x) { return x > 0.f ? x : SLOPE * x; }

__device__ __forceinline__ bfu f2bf(float f) {
    unsigned int u = __float_as_uint(f);
    u += 0x7FFFu + ((u >> 16) & 1u);          // round-to-nearest-even
    return (bfu)(u >> 16);
}
__device__ __forceinline__ float bf2f(bfu s) {
    return __uint_as_float(((unsigned int)s) << 16);
}
__device__ __forceinline__ float bflo(unsigned int u) { return __uint_as_float(u << 16); }
__device__ __forceinline__ float bfhi(unsigned int u) { return __uint_as_float(u & 0xFFFF0000u); }

// ---------------------------------------------------------------------------
// Tiled node GEMM: 64 nodes/block, thread = 4 nodes x 4 outputs.
// Output table in bf16 (for gather consumers). MODE 1: es/ed head-dot epilogue.
// ---------------------------------------------------------------------------
template<int KIN, int MODE>
__global__ __launch_bounds__(256)
void gemm_tile(const float* __restrict__ in, const float* __restrict__ W,
               bfu* __restrict__ outB,
               const float* __restrict__ a_s, const float* __restrict__ a_d,
               float* __restrict__ es, float* __restrict__ ed)
{
    __shared__ float Ws[KIN * 64];
    __shared__ float rows[64 * (KIN + 1)];
    int t = threadIdx.x;
    int base = blockIdx.x * 64;
    {
        const float4* Wv = (const float4*)W;
        float4* Wsv = (float4*)Ws;
        for (int i = t; i < KIN * 16; i += 256) Wsv[i] = Wv[i];
    }
    constexpr int RQ = KIN / 4;
    for (int i = t; i < 64 * RQ; i += 256) {
        int r = i / RQ, c = (i % RQ) * 4;
        int n = base + r;
        float4 v = make_float4(0.f, 0.f, 0.f, 0.f);
        if (n < N_NODES) v = *(const float4*)(in + (size_t)n * KIN + c);
        float* dp = rows + r * (KIN + 1) + c;
        dp[0] = v.x; dp[1] = v.y; dp[2] = v.z; dp[3] = v.w;
    }
    __syncthreads();
    int tr = t >> 4, tc = t & 15;
    float acc[4][4] = {};
    const float4* Wsv = (const float4*)Ws;
#pragma unroll 8
    for (int k = 0; k < KIN; ++k) {
        float4 w = Wsv[k * 16 + tc];
        float rv[4];
#pragma unroll
        for (int i = 0; i < 4; ++i) rv[i] = rows[(tr * 4 + i) * (KIN + 1) + k];
#pragma unroll
        for (int i = 0; i < 4; ++i) {
            acc[i][0] = fmaf(rv[i], w.x, acc[i][0]);
            acc[i][1] = fmaf(rv[i], w.y, acc[i][1]);
            acc[i][2] = fmaf(rv[i], w.z, acc[i][2]);
            acc[i][3] = fmaf(rv[i], w.w, acc[i][3]);
        }
    }
    int j0 = tc * 4;
#pragma unroll
    for (int i = 0; i < 4; ++i) {
        int n = base + tr * 4 + i;
        if (n < N_NODES) {
            ushort4 ov;
            ov.x = f2bf(acc[i][0]); ov.y = f2bf(acc[i][1]);
            ov.z = f2bf(acc[i][2]); ov.w = f2bf(acc[i][3]);
            *(ushort4*)(outB + (size_t)n * 64 + j0) = ov;
        }
    }
    if (MODE == 1) {
        float s0[4], s1[4];
#pragma unroll
        for (int i = 0; i < 4; ++i) {
            float pes = 0.f, ped = 0.f;
#pragma unroll
            for (int q = 0; q < 4; ++q) {
                pes = fmaf(acc[i][q], a_s[j0 + q], pes);
                ped = fmaf(acc[i][q], a_d[j0 + q], ped);
            }
            pes += __shfl_xor(pes, 1, 64);
            ped += __shfl_xor(ped, 1, 64);
            s0[i] = pes; s1[i] = ped;
        }
        if ((tc & 1) == 0) {
            int h = tc >> 1;
#pragma unroll
            for (int i = 0; i < 4; ++i) {
                int n = base + tr * 4 + i;
                if (n < N_NODES) {
                    es[n * NH + h] = s0[i];
                    ed[n * NH + h] = s1[i];
                }
            }
        }
    }
}

// ---------------------------------------------------------------------------
// Dual node GEMM (shared fp32 input, two weight mats, bf16 outputs).
// SCALED: out_i *= sc_i[n].
// ---------------------------------------------------------------------------
template<int SCALED>
__global__ __launch_bounds__(256)
void gemm_dual(const float* __restrict__ in, const float* __restrict__ W0,
               const float* __restrict__ W1,
               const float* __restrict__ sc0, const float* __restrict__ sc1,
               bfu* __restrict__ out0, bfu* __restrict__ out1)
{
    __shared__ float Ws[2 * 64 * 64];
    __shared__ float rows[64 * 65];
    int t = threadIdx.x;
    int base = blockIdx.x * 64;
    {
        const float4* W0v = (const float4*)W0;
        const float4* W1v = (const float4*)W1;
        float4* Wsv = (float4*)Ws;
        for (int i = t; i < 1024; i += 256) { Wsv[i] = W0v[i]; Wsv[1024 + i] = W1v[i]; }
    }
    for (int i = t; i < 64 * 16; i += 256) {
        int r = i / 16, c = (i % 16) * 4;
        int n = base + r;
        float4 v = make_float4(0.f, 0.f, 0.f, 0.f);
        if (n < N_NODES) v = *(const float4*)(in + (size_t)n * 64 + c);
        float* dp = rows + r * 65 + c;
        dp[0] = v.x; dp[1] = v.y; dp[2] = v.z; dp[3] = v.w;
    }
    __syncthreads();
    int tr = t >> 4, tc = t & 15;
    float a0[4][4] = {}, a1[4][4] = {};
    const float4* Wsv = (const float4*)Ws;
#pragma unroll 4
    for (int k = 0; k < 64; ++k) {
        float4 w0 = Wsv[k * 16 + tc];
        float4 w1 = Wsv[1024 + k * 16 + tc];
        float rv[4];
#pragma unroll
        for (int i = 0; i < 4; ++i) rv[i] = rows[(tr * 4 + i) * 65 + k];
#pragma unroll
        for (int i = 0; i < 4; ++i) {
            a0[i][0] = fmaf(rv[i], w0.x, a0[i][0]);
            a0[i][1] = fmaf(rv[i], w0.y, a0[i][1]);
            a0[i][2] = fmaf(rv[i], w0.z, a0[i][2]);
            a0[i][3] = fmaf(rv[i], w0.w, a0[i][3]);
            a1[i][0] = fmaf(rv[i], w1.x, a1[i][0]);
            a1[i][1] = fmaf(rv[i], w1.y, a1[i][1]);
            a1[i][2] = fmaf(rv[i], w1.z, a1[i][2]);
            a1[i][3] = fmaf(rv[i], w1.w, a1[i][3]);
        }
    }
    int j0 = tc * 4;
#pragma unroll
    for (int i = 0; i < 4; ++i) {
        int n = base + tr * 4 + i;
        if (n >= N_NODES) continue;
        float m0 = 1.f, m1 = 1.f;
        if (SCALED) { m0 = sc0[n]; m1 = sc1[n]; }
        ushort4 o0, o1;
        o0.x = f2bf(a0[i][0] * m0); o0.y = f2bf(a0[i][1] * m0);
        o0.z = f2bf(a0[i][2] * m0); o0.w = f2bf(a0[i][3] * m0);
        o1.x = f2bf(a1[i][0] * m1); o1.y = f2bf(a1[i][1] * m1);
        o1.z = f2bf(a1[i][2] * m1); o1.w = f2bf(a1[i][3] * m1);
        *(ushort4*)(out0 + (size_t)n * 64 + j0) = o0;
        *(ushort4*)(out1 + (size_t)n * 64 + j0) = o1;
    }
}

// ---------------------------------------------------------------------------
// CSR build: histogram -> scan -> scatter (+ dst array)
// ---------------------------------------------------------------------------
__global__ void csr_hist(const int* __restrict__ ei, int* __restrict__ cnt)
{
    int e = blockIdx.x * 256 + threadIdx.x;
    if (e >= E_EDGES) return;
    atomicAdd(&cnt[ei[E_EDGES + e]], 1);
}

__global__ void csr_scan1(const int* __restrict__ cnt, int* __restrict__ offs,
                          int* __restrict__ bsum)
{
    __shared__ int tmp[256];
    int t = threadIdx.x;
    int i = blockIdx.x * 256 + t;
    int v = (i < N_NODES) ? cnt[i] + 1 : 0;
    tmp[t] = v; __syncthreads();
#pragma unroll
    for (int o = 1; o < 256; o <<= 1) {
        int a = (t >= o) ? tmp[t - o] : 0;
        __syncthreads();
        tmp[t] += a;
        __syncthreads();
    }
    if (i < N_NODES) offs[i] = tmp[t] - v;
    if (t == 255) bsum[blockIdx.x] = tmp[255];
}

__global__ void csr_scan2(int* __restrict__ bsum)
{
    __shared__ int tmp[512];
    int t = threadIdx.x;
    int v = (t < NSCAN_BLK) ? bsum[t] : 0;
    tmp[t] = v; __syncthreads();
#pragma unroll
    for (int o = 1; o < 512; o <<= 1) {
        int a = (t >= o) ? tmp[t - o] : 0;
        __syncthreads();
        tmp[t] += a;
        __syncthreads();
    }
    if (t < NSCAN_BLK) bsum[t] = tmp[t] - v;
}

__global__ void csr_scan3(int* __restrict__ offs, const int* __restrict__ bsum,
                          int* __restrict__ cursor)
{
    int i = blockIdx.x * 256 + threadIdx.x;
    if (i < N_NODES) {
        int v = offs[i] + bsum[blockIdx.x];
        offs[i] = v;
        cursor[i] = v;
    }
    if (i == 0) offs[N_NODES] = E2;
}

__global__ void csr_scatter(const int* __restrict__ ei, int* __restrict__ cursor,
                            int* __restrict__ csr, int* __restrict__ csrd)
{
    int e = blockIdx.x * 256 + threadIdx.x;
    if (e >= E2) return;
    int d, tag;
    if (e < E_EDGES) { int s = ei[e]; d = ei[E_EDGES + e]; tag = s; }
    else             { d = e - E_EDGES; tag = d | SELF_FLAG; }
    int pos = atomicAdd(&cursor[d], 1);
    csr[pos] = tag;
    csrd[pos] = d;
}

// ---------------------------------------------------------------------------
// Fused GAT aggregate: wave per dst node; 4 edge-slots x 16 feature-lanes.
// Single pass (no segment-max; logits O(1)). bf16 gather, fp32 accumulate.
// ---------------------------------------------------------------------------
template<int ELU>
__global__ void gat_aggregate4(const int* __restrict__ offs, const int* __restrict__ csr,
                               const float* __restrict__ es, const float* __restrict__ ed,
                               const bfu* __restrict__ hsrcB, const float* __restrict__ bias,
                               float* __restrict__ out)
{
    int n = blockIdx.x * 4 + (threadIdx.x >> 6);
    int lane = threadIdx.x & 63;
    if (n >= N_NODES) return;
    int g  = lane >> 4;        // edge slot 0..3
    int fl = lane & 15;        // feature chunk: features fl*4 .. fl*4+3
    int h  = fl >> 1;          // head
    int beg = offs[n], end = offs[n + 1];
    float edv = ed[n * NH + h];
    float den = 0.f;
    float4 acc = make_float4(0.f, 0.f, 0.f, 0.f);
    for (int p = beg + g; p < end; p += 4) {
        int s = csr[p] & SRC_MASK;
        float l = lrelu(es[s * NH + h] + edv);
        float ex = __expf(l);
        den += ex;
        ushort4 rb = *(const ushort4*)(hsrcB + (size_t)s * HD + fl * 4);
        acc.x = fmaf(bf2f(rb.x), ex, acc.x);
        acc.y = fmaf(bf2f(rb.y), ex, acc.y);
        acc.z = fmaf(bf2f(rb.z), ex, acc.z);
        acc.w = fmaf(bf2f(rb.w), ex, acc.w);
    }
#pragma unroll
    for (int o = 16; o <= 32; o <<= 1) {
        den   += __shfl_xor(den,   o, 64);
        acc.x += __shfl_xor(acc.x, o, 64);
        acc.y += __shfl_xor(acc.y, o, 64);
        acc.z += __shfl_xor(acc.z, o, 64);
        acc.w += __shfl_xor(acc.w, o, 64);
    }
    if (g == 0) {
        float inv = 1.f / (den + 1e-16f);
        float4 bv = *(const float4*)(bias + fl * 4);
        float v0 = acc.x * inv + bv.x;
        float v1 = acc.y * inv + bv.y;
        float v2 = acc.z * inv + bv.z;
        float v3 = acc.w * inv + bv.w;
        if (ELU) {
            v0 = v0 > 0.f ? v0 : (__expf(v0) - 1.f);
            v1 = v1 > 0.f ? v1 : (__expf(v1) - 1.f);
            v2 = v2 > 0.f ? v2 : (__expf(v2) - 1.f);
            v3 = v3 > 0.f ? v3 : (__expf(v3) - 1.f);
        }
        *(float4*)(out + (size_t)n * HD + fl * 4) = make_float4(v0, v1, v2, v3);
    }
}

// ---------------------------------------------------------------------------
// node attention, tiled: 64 nodes/block, w1+rows staged in LDS.
// ---------------------------------------------------------------------------
__global__ __launch_bounds__(256)
void node_att_tile(const float* __restrict__ H, const float* __restrict__ w1,
                   const float* __restrict__ b1, const float* __restrict__ w2,
                   const float* __restrict__ b2, float* __restrict__ ac,
                   float* __restrict__ at)
{
    __shared__ float w1s[64 * 32];
    __shared__ float w2s[64];
    __shared__ float rows[64 * 65];
    int t = threadIdx.x;
    int base = blockIdx.x * 64;
    {
        const float4* w1v = (const float4*)w1;
        float4* dst = (float4*)w1s;
        for (int i = t; i < 512; i += 256) dst[i] = w1v[i];
    }
    if (t < 64) w2s[t] = w2[t];
    for (int i = t; i < 64 * 16; i += 256) {
        int r = i >> 4, c = (i & 15) * 4;
        int n = base + r;
        float4 v = make_float4(0.f, 0.f, 0.f, 0.f);
        if (n < N_NODES) v = *(const float4*)(H + (size_t)n * 64 + c);
        float* dp = rows + r * 65 + c;
        dp[0] = v.x; dp[1] = v.y; dp[2] = v.z; dp[3] = v.w;
    }
    __syncthreads();
    int tr = t >> 3;
    int tc = t & 7;
    float4 bv = *(const float4*)(b1 + tc * 4);
    float4 acc0 = bv, acc1 = bv;
    const float4* w1sv = (const float4*)w1s;
#pragma unroll 8
    for (int k = 0; k < 64; ++k) {
        float4 w = w1sv[k * 8 + tc];
        float r0 = rows[tr * 65 + k];
        float r1 = rows[(tr + 32) * 65 + k];
        acc0.x = fmaf(r0, w.x, acc0.x); acc0.y = fmaf(r0, w.y, acc0.y);
        acc0.z = fmaf(r0, w.z, acc0.z); acc0.w = fmaf(r0, w.w, acc0.w);
        acc1.x = fmaf(r1, w.x, acc1.x); acc1.y = fmaf(r1, w.y, acc1.y);
        acc1.z = fmaf(r1, w.z, acc1.z); acc1.w = fmaf(r1, w.w, acc1.w);
    }
    float z00 = 0.f, z01 = 0.f, z10 = 0.f, z11 = 0.f;
    float h0, w20, w21;
    int j0 = tc * 4;
#pragma unroll
    for (int q = 0; q < 4; ++q) {
        float a0q = q == 0 ? acc0.x : q == 1 ? acc0.y : q == 2 ? acc0.z : acc0.w;
        float a1q = q == 0 ? acc1.x : q == 1 ? acc1.y : q == 2 ? acc1.z : acc1.w;
        w20 = w2s[(j0 + q) * 2]; w21 = w2s[(j0 + q) * 2 + 1];
        h0 = fmaxf(a0q, 0.f);
        z00 = fmaf(h0, w20, z00); z01 = fmaf(h0, w21, z01);
        h0 = fmaxf(a1q, 0.f);
        z10 = fmaf(h0, w20, z10); z11 = fmaf(h0, w21, z11);
    }
#pragma unroll
    for (int o = 1; o < 8; o <<= 1) {
        z00 += __shfl_xor(z00, o, 64); z01 += __shfl_xor(z01, o, 64);
        z10 += __shfl_xor(z10, o, 64); z11 += __shfl_xor(z11, o, 64);
    }
    if (tc == 0) {
        int n0 = base + tr, n1 = base + tr + 32;
        if (n0 < N_NODES) {
            float zz0 = z00 + b2[0], zz1 = z01 + b2[1];
            float mx = fmaxf(zz0, zz1);
            float e0 = __expf(zz0 - mx), e1 = __expf(zz1 - mx);
            float ss = e0 + e1;
            ac[n0] = e0 / ss; at[n0] = e1 / ss;
        }
        if (n1 < N_NODES) {
            float zz0 = z10 + b2[0], zz1 = z11 + b2[1];
            float mx = fmaxf(zz0, zz1);
            float e0 = __expf(zz0 - mx), e1 = __expf(zz1 - mx);
            float ss = e0 + e1;
            ac[n1] = e0 / ss; at[n1] = e1 / ss;
        }
    }
}

// ---------------------------------------------------------------------------
// edge attention, flat over CSR: 8 lanes/edge, bf16 P1/P2 gather. NO atomics.
// ---------------------------------------------------------------------------
__global__ __launch_bounds__(256)
void edge_att_flat(const int* __restrict__ csr, const int* __restrict__ csrd,
                   const bfu* __restrict__ P1b, const bfu* __restrict__ P2b,
                   const float* __restrict__ b1, const float* __restrict__ w2,
                   const float* __restrict__ b2,
                   float* __restrict__ bc, float* __restrict__ bt)
{
    int lane = threadIdx.x & 63;
    int sg = lane >> 3, q = lane & 7;
    int p = (blockIdx.x * 4 + (threadIdx.x >> 6)) * 8 + sg;
    if (p >= E2) return;
    int sv = csr[p];
    if (sv & SELF_FLAG) return;
    int d = csrd[p];
    uint4 U1 = *(const uint4*)(P1b + (size_t)sv * 64 + q * 8);
    uint4 U2 = *(const uint4*)(P2b + (size_t)d  * 64 + q * 8);
    const float4* pb = (const float4*)(b1 + q * 8);
    const float4* pw = (const float4*)(w2 + q * 16);
    float4 c0 = pb[0], c1 = pb[1];
    float4 w0 = pw[0], w1v = pw[1], w2v = pw[2], w3v = pw[3];
    float h0 = fmaxf(bflo(U1.x) + bflo(U2.x) + c0.x, 0.f);
    float h1 = fmaxf(bfhi(U1.x) + bfhi(U2.x) + c0.y, 0.f);
    float h2 = fmaxf(bflo(U1.y) + bflo(U2.y) + c0.z, 0.f);
    float h3 = fmaxf(bfhi(U1.y) + bfhi(U2.y) + c0.w, 0.f);
    float h4 = fmaxf(bflo(U1.z) + bflo(U2.z) + c1.x, 0.f);
    float h5 = fmaxf(bfhi(U1.z) + bfhi(U2.z) + c1.y, 0.f);
    float h6 = fmaxf(bflo(U1.w) + bflo(U2.w) + c1.z, 0.f);
    float h7 = fmaxf(bfhi(U1.w) + bfhi(U2.w) + c1.w, 0.f);
    float z0 = h0 * w0.x + h1 * w0.z + h2 * w1v.x + h3 * w1v.z
             + h4 * w2v.x + h5 * w2v.z + h6 * w3v.x + h7 * w3v.z;
    float z1 = h0 * w0.y + h1 * w0.w + h2 * w1v.y + h3 * w1v.w
             + h4 * w2v.y + h5 * w2v.w + h6 * w3v.y + h7 * w3v.w;
    z0 += __shfl_xor(z0, 1, 64); z1 += __shfl_xor(z1, 1, 64);
    z0 += __shfl_xor(z0, 2, 64); z1 += __shfl_xor(z1, 2, 64);
    z0 += __shfl_xor(z0, 4, 64); z1 += __shfl_xor(z1, 4, 64);
    if (q == 0) {
        z0 += b2[0]; z1 += b2[1];
        float mx = fmaxf(z0, z1);
        float e0 = __expf(z0 - mx), e1 = __expf(z1 - mx);
        float ss = e0 + e1;
        bc[p] = e0 / ss;
        bt[p] = e1 / ss;
    }
}

// ---------------------------------------------------------------------------
// GCN: per-node degree gather (no atomics) -> dis; then per-edge norms
// ---------------------------------------------------------------------------
__global__ void gcn_deg_dis(const int* __restrict__ offs, const int* __restrict__ csr,
                            const float* __restrict__ bc, const float* __restrict__ bt,
                            float* __restrict__ disc, float* __restrict__ dist)
{
    int n = blockIdx.x * 256 + threadIdx.x;
    if (n >= N_NODES) return;
    int beg = offs[n], end = offs[n + 1];
    float dc = 0.f, dt = 0.f;
    for (int p = beg; p < end; ++p) {
        if (csr[p] & SELF_FLAG) { dc += 1.f; dt += 1.f; }
        else { dc += bc[p]; dt += bt[p]; }
    }
    disc[n] = rsqrtf(fmaxf(dc, 1e-20f));   // deg >= 1 (self loop)
    dist[n] = rsqrtf(fmaxf(dt, 1e-20f));
}

__global__ void gcn_norm(const int* __restrict__ csr, const int* __restrict__ csrd,
                         const float* __restrict__ disc, const float* __restrict__ dist,
                         float* __restrict__ bc, float* __restrict__ bt)
{
    int p = blockIdx.x * 256 + threadIdx.x;
    if (p >= E2) return;
    int sv = csr[p];
    int s = sv & SRC_MASK;
    int d = csrd[p];
    float wc, wt;
    if (sv & SELF_FLAG) { wc = 1.f; wt = 1.f; }
    else { wc = bc[p]; wt = bt[p]; }
    bc[p] = disc[s] * wc * disc[d];
    bt[p] = dist[s] * wt * dist[d];
}

__global__ void gcn_aggregate_both(const int* __restrict__ offs, const int* __restrict__ csr,
                                   const bfu* __restrict__ preC, const bfu* __restrict__ preT,
                                   const float* __restrict__ nrmC, const float* __restrict__ nrmT,
                                   float* __restrict__ outC, float* __restrict__ outT)
{
    int n = blockIdx.x * 4 + (threadIdx.x >> 6);
    int lane = threadIdx.x & 63;
    if (n >= N_NODES) return;
    int g  = lane >> 4;
    int fl = lane & 15;
    int beg = offs[n], end = offs[n + 1];
    float4 a1 = make_float4(0.f, 0.f, 0.f, 0.f);
    float4 a2 = make_float4(0.f, 0.f, 0.f, 0.f);
    for (int p = beg + g; p < end; p += 4) {
        int s = csr[p] & SRC_MASK;
        float wc = nrmC[p], wt = nrmT[p];
        ushort4 rc = *(const ushort4*)(preC + (size_t)s * HD + fl * 4);
        ushort4 rt = *(const ushort4*)(preT + (size_t)s * HD + fl * 4);
        a1.x = fmaf(bf2f(rc.x), wc, a1.x);
        a1.y = fmaf(bf2f(rc.y), wc, a1.y);
        a1.z = fmaf(bf2f(rc.z), wc, a1.z);
        a1.w = fmaf(bf2f(rc.w), wc, a1.w);
        a2.x = fmaf(bf2f(rt.x), wt, a2.x);
        a2.y = fmaf(bf2f(rt.y), wt, a2.y);
        a2.z = fmaf(bf2f(rt.z), wt, a2.z);
        a2.w = fmaf(bf2f(rt.w), wt, a2.w);
    }
#pragma unroll
    for (int o = 16; o <= 32; o <<= 1) {
        a1.x += __shfl_xor(a1.x, o, 64); a1.y += __shfl_xor(a1.y, o, 64);
        a1.z += __shfl_xor(a1.z, o, 64); a1.w += __shfl_xor(a1.w, o, 64);
        a2.x += __shfl_xor(a2.x, o, 64); a2.y += __shfl_xor(a2.y, o, 64);
        a2.z += __shfl_xor(a2.z, o, 64); a2.w += __shfl_xor(a2.w, o, 64);
    }
    if (g == 0) {
        *(float4*)(outC + (size_t)n * HD + fl * 4) = a1;
        *(float4*)(outT + (size_t)n * HD + fl * 4) = a2;
    }
}

// ---------------------------------------------------------------------------
// readout (both branches): wave per 8 consecutive nodes (high occupancy)
// ---------------------------------------------------------------------------
#define RO_CHUNK 8
__global__ void readout_both(const float* __restrict__ Gc, const float* __restrict__ Gt,
                             const int* __restrict__ batch,
                             float* __restrict__ S_c, float* __restrict__ S_t,
                             float* __restrict__ cnt)
{
    int chunk = blockIdx.x * 4 + (threadIdx.x >> 6);
    int lane = threadIdx.x & 63;
    int n0 = chunk * RO_CHUNK;
    if (n0 >= N_NODES) return;
    int n1 = n0 + RO_CHUNK; if (n1 > N_NODES) n1 = N_NODES;
    int gp = batch[n0];
    float a1 = 0.f, a2 = 0.f; int rc = 0;
    for (int n = n0; n < n1; ++n) {
        int g = batch[n];
        if (g != gp) {
            atomicAdd(&S_c[gp * 64 + lane], a1);
            atomicAdd(&S_t[gp * 64 + lane], a2);
            if (lane == 0) atomicAdd(&cnt[gp], (float)rc);
            a1 = a2 = 0.f; rc = 0; gp = g;
        }
        a1 += Gc[(size_t)n * 64 + lane];
        a2 += Gt[(size_t)n * 64 + lane];
        ++rc;
    }
    atomicAdd(&S_c[gp * 64 + lane], a1);
    atomicAdd(&S_t[gp * 64 + lane], a2);
    if (lane == 0) atomicAdd(&cnt[gp], (float)rc);
}

// ---------------------------------------------------------------------------
// final per-graph heads
// ---------------------------------------------------------------------------
__global__ void final_head(const float* __restrict__ S_c, const float* __restrict__ S_t,
                           const float* __restrict__ cnt,
                           const float* __restrict__ gc_b, const float* __restrict__ gt_b,
                           const float* __restrict__ rc_w, const float* __restrict__ rc_b,
                           const float* __restrict__ rt_w, const float* __restrict__ rt_b,
                           const float* __restrict__ cc_w1, const float* __restrict__ cc_b1,
                           const float* __restrict__ cc_w2, const float* __restrict__ cc_b2,
                           const float* __restrict__ ct_w1, const float* __restrict__ ct_b1,
                           const float* __restrict__ ct_w2, const float* __restrict__ ct_b2,
                           const float* __restrict__ cm_w1, const float* __restrict__ cm_b1,
                           const float* __restrict__ cm_w2, const float* __restrict__ cm_b2,
                           float* __restrict__ out)
{
    int g = blockIdx.x;
    int j = threadIdx.x;
    __shared__ float sc[64], st[64], hgc[64], hgt[64], hid[64];
    float c = cnt[g];
    sc[j] = S_c[g * 64 + j] + c * gc_b[j];
    st[j] = S_t[g * 64 + j] + c * gt_b[j];
    __syncthreads();
    float acr = c * rc_b[j], atr = c * rt_b[j];
#pragma unroll 8
    for (int k = 0; k < 64; ++k) {
        acr = fmaf(sc[k], rc_w[k * 64 + j], acr);
        atr = fmaf(st[k], rt_w[k * 64 + j], atr);
    }
    hgc[j] = acr; hgt[j] = atr;
    out[3840 + g * 64 + j]  = acr;
    out[12032 + g * 64 + j] = atr;
    __syncthreads();
    float hv = 0.f;
    if (j < 32) {
        float a = cc_b1[j];
#pragma unroll 8
        for (int k = 0; k < 64; ++k) a = fmaf(hgc[k], cc_w1[k * 32 + j], a);
        hv = fmaxf(a, 0.f);
    }
    hid[j] = hv;
    __syncthreads();
    if (j < NC) {
        float a = cc_b2[j];
#pragma unroll
        for (int k = 0; k < 32; ++k) a = fmaf(hid[k], cc_w2[k * NC + j], a);
        out[g * NC + j] = a;
    }
    __syncthreads();
    hv = 0.f;
    if (j < 32) {
        float a = ct_b1[j];
#pragma unroll 8
        for (int k = 0; k < 64; ++k) a = fmaf(hgt[k], ct_w1[k * 32 + j], a);
        hv = fmaxf(a, 0.f);
    }
    hid[j] = hv;
    __syncthreads();
    if (j < NC) {
        float a = ct_b2[j];
#pragma unroll
        for (int k = 0; k < 32; ++k) a = fmaf(hid[k], ct_w2[k * NC + j], a);
        out[1280 + g * NC + j] = a;
    }
    __syncthreads();
    {
        float a = cm_b1[j];
#pragma unroll 8
        for (int k = 0; k < 64; ++k) {
            a = fmaf(hgc[k], cm_w1[k * 64 + j], a);
            a = fmaf(hgt[k], cm_w1[(64 + k) * 64 + j], a);
        }
        hid[j] = fmaxf(a, 0.f);
    }
    __syncthreads();
    if (j < NC) {
        float a = cm_b2[j];
#pragma unroll 8
        for (int k = 0; k < 64; ++k) a = fmaf(hid[k], cm_w2[k * NC + j], a);
        out[2560 + g * NC + j] = a;
    }
}

// ---------------------------------------------------------------------------
extern "C" void kernel_launch(void* const* d_in, const int* in_sizes, int n_in,
                              void* d_out, int out_size, void* d_ws, size_t ws_size,
                              hipStream_t stream)
{
    const float* x     = (const float*)d_in[0];
    const int*   ei    = (const int*)d_in[1];
    const int*   batch = (const int*)d_in[2];
    const float* W1    = (const float*)d_in[3];
    const float* as1   = (const float*)d_in[4];
    const float* ad1   = (const float*)d_in[5];
    const float* b1    = (const float*)d_in[6];
    const float* W2    = (const float*)d_in[7];
    const float* as2   = (const float*)d_in[8];
    const float* ad2   = (const float*)d_in[9];
    const float* b2    = (const float*)d_in[10];
    const float* na_w1 = (const float*)d_in[11];
    const float* na_b1 = (const float*)d_in[12];
    const float* na_w2 = (const float*)d_in[13];
    const float* na_b2 = (const float*)d_in[14];
    const float* ea_w1 = (const float*)d_in[15];
    const float* ea_b1 = (const float*)d_in[16];
    const float* ea_w2 = (const float*)d_in[17];
    const float* ea_b2 = (const float*)d_in[18];
    const float* gc_w  = (const float*)d_in[19];
    const float* gc_b  = (const float*)d_in[20];
    const float* gt_w  = (const float*)d_in[21];
    const float* gt_b  = (const float*)d_in[22];
    const float* rc_w  = (const float*)d_in[23];
    const float* rc_b  = (const float*)d_in[24];
    const float* rt_w  = (const float*)d_in[25];
    const float* rt_b  = (const float*)d_in[26];
    const float* cc_w1 = (const float*)d_in[27];
    const float* cc_b1 = (const float*)d_in[28];
    const float* cc_w2 = (const float*)d_in[29];
    const float* cc_b2 = (const float*)d_in[30];
    const float* ct_w1 = (const float*)d_in[31];
    const float* ct_b1 = (const float*)d_in[32];
    const float* ct_w2 = (const float*)d_in[33];
    const float* ct_b2 = (const float*)d_in[34];
    const float* cm_w1 = (const float*)d_in[35];
    const float* cm_b1 = (const float*)d_in[36];
    const float* cm_w2 = (const float*)d_in[37];
    const float* cm_b2 = (const float*)d_in[38];
    float* out = (float*)d_out;

    float* ws = (float*)d_ws;
    size_t o = 0;
    const size_t nf = (size_t)N_NODES * HD;
    float* T1   = ws + o; o += nf;             // H1 / Gc-agg out
    float* T2   = ws + o; o += nf;             // H  / Gt-agg out
    float* es   = ws + o; o += (size_t)N_NODES * NH;
    float* ed   = ws + o; o += (size_t)N_NODES * NH;
    float* ac   = ws + o; o += N_NODES;
    float* at   = ws + o; o += N_NODES;
    float* bc   = ws + o; o += E2;             // beta_c -> norm_c (in place)
    float* bt   = ws + o; o += E2;             // beta_t -> norm_t (in place)
    float* degc = ws + o; o += N_NODES;        // dis_c
    float* degt = ws + o; o += N_NODES;        // dis_t
    float* S_c  = ws + o; o += NG * 64;
    float* S_t  = ws + o; o += NG * 64;
    float* cntf = ws + o; o += NG;
    bfu* B0     = (bfu*)(ws + o); o += nf / 2; // bf16 gather table
    bfu* B1     = (bfu*)(ws + o); o += nf / 2; // bf16 gather table
    int* csr    = (int*)(ws + o); o += E2;
    int* csrd   = (int*)(ws + o); o += E2;
    int* offs   = (int*)(ws + o); o += N_NODES + 1;
    int* cnt    = (int*)at;
    int* cursor = (int*)ac;
    int* bsum   = (int*)degc;   // consumed before degc written

    const int NW_BLKS = N_NODES / 4;             // 25000
    const int NT_BLKS = (N_NODES + 255) / 256;   // 391
    const int E_BLKS  = (E2 + 255) / 256;        // 3516
    const int EF_BLKS = (E2 + 31) / 32;          // 28125
    const int RO_BLKS = (N_NODES / RO_CHUNK) / 4;  // 3125

    // ---------------- CSR build ----------------
    hipMemsetAsync(cnt, 0, (size_t)N_NODES * 4, stream);
    csr_hist<<<(E_EDGES + 255) / 256, 256, 0, stream>>>(ei, cnt);
    csr_scan1<<<NSCAN_BLK, 256, 0, stream>>>(cnt, offs, bsum);
    csr_scan2<<<1, 512, 0, stream>>>(bsum);
    csr_scan3<<<NSCAN_BLK, 256, 0, stream>>>(offs, bsum, cursor);
    csr_scatter<<<E_BLKS, 256, 0, stream>>>(ei, cursor, csr, csrd);

    // ---------------- GAT layer 1 ----------------
    gemm_tile<FIN, 1><<<NBLK64, 256, 0, stream>>>(x, W1, B0, as1, ad1, es, ed);
    gat_aggregate4<1><<<NW_BLKS, 256, 0, stream>>>(offs, csr, es, ed, B0, b1, T1);

    // ---------------- GAT layer 2 ----------------
    gemm_tile<64, 1><<<NBLK64, 256, 0, stream>>>(T1, W2, B0, as2, ad2, es, ed);
    gat_aggregate4<0><<<NW_BLKS, 256, 0, stream>>>(offs, csr, es, ed, B0, b2, T2);

    // ---------------- node attention ----------------
    node_att_tile<<<NBLK64, 256, 0, stream>>>(T2, na_w1, na_b1, na_w2, na_b2, ac, at);

    // ---------------- edge attention (P1 -> B0, P2 -> B1, bf16) -------------
    gemm_dual<0><<<NBLK64, 256, 0, stream>>>(T2, ea_w1, ea_w1 + 64 * 64,
                                             nullptr, nullptr, B0, B1);
    edge_att_flat<<<EF_BLKS, 256, 0, stream>>>(csr, csrd, B0, B1, ea_b1, ea_w2, ea_b2, bc, bt);

    // ---------------- GCN norm (bc/bt -> per-edge norms in place) -----------
    gcn_deg_dis<<<NT_BLKS, 256, 0, stream>>>(offs, csr, bc, bt, degc, degt);
    gcn_norm<<<E_BLKS, 256, 0, stream>>>(csr, csrd, degc, degt, bc, bt);

    hipMemsetAsync(S_c, 0, (size_t)(2 * NG * 64 + NG) * 4, stream);

    // ---------------- GCN pre-transforms (pre_c -> B0, pre_t -> B1) ---------
    gemm_dual<1><<<NBLK64, 256, 0, stream>>>(T2, gc_w, gt_w, ac, at, B0, B1);

    // ---------------- GCN aggregate (both) + readout ------------------------
    gcn_aggregate_both<<<NW_BLKS, 256, 0, stream>>>(offs, csr, B0, B1, bc, bt, T1, T2);
    readout_both<<<RO_BLKS, 256, 0, stream>>>(T1, T2, batch, S_c, S_t, cntf);

    // ---------------- heads ----------------
    final_head<<<NG, 64, 0, stream>>>(S_c, S_t, cntf,
                                      gc_b, gt_b, rc_w, rc_b, rt_w, rt_b,
                                      cc_w1, cc_b1, cc_w2, cc_b2,
                                      ct_w1, ct_b1, ct_w2, ct_b2,
                                      cm_w1, cm_b1, cm_w2, cm_b2, out);
    (void)in_sizes; (void)n_in; (void)out_size; (void)ws_size;
}

// Round 9
// 616.718 us; speedup vs baseline: 1.1120x; 1.0631x over previous
//
#include <hip/hip_runtime.h>
#include <hip/hip_bf16.h>

#define N_NODES 100000
#define E_EDGES 800000
#define E2 (E_EDGES + N_NODES)   // 900000 edges incl. self loops
#define FIN 128
#define HD 64
#define NH 8
#define NG 128
#define NC 10
#define SLOPE 0.2f
#define SELF_FLAG 0x40000000
#define SRC_MASK  0x3FFFFFFF
#define NSCAN_BLK 391            // ceil(N/256)
#define NBLK64 1563              // ceil(N/64)

typedef unsigned short bfu;

__device__ __forceinline__ float lrelu(float x) { return x > 0.f ? x : SLOPE * x; }

__device__ __forceinline__ bfu f2bf(float f) {
    unsigned int u = __float_as_uint(f);
    u += 0x7FFFu + ((u >> 16) & 1u);          // round-to-nearest-even
    return (bfu)(u >> 16);
}
__device__ __forceinline__ float bf2f(bfu s) {
    return __uint_as_float(((unsigned int)s) << 16);
}
__device__ __forceinline__ float bflo(unsigned int u) { return __uint_as_float(u << 16); }
__device__ __forceinline__ float bfhi(unsigned int u) { return __uint_as_float(u & 0xFFFF0000u); }

// ---------------------------------------------------------------------------
// Tiled node GEMM: 64 nodes/block, thread = 4 nodes x 4 outputs.
// Output table in bf16 (for gather consumers). MODE 1: es/ed head-dot epilogue.
// ---------------------------------------------------------------------------
template<int KIN, int MODE>
__global__ __launch_bounds__(256)
void gemm_tile(const float* __restrict__ in, const float* __restrict__ W,
               bfu* __restrict__ outB,
               const float* __restrict__ a_s, const float* __restrict__ a_d,
               float* __restrict__ es, float* __restrict__ ed)
{
    __shared__ float Ws[KIN * 64];
    __shared__ float rows[64 * (KIN + 1)];
    int t = threadIdx.x;
    int base = blockIdx.x * 64;
    {
        const float4* Wv = (const float4*)W;
        float4* Wsv = (float4*)Ws;
        for (int i = t; i < KIN * 16; i += 256) Wsv[i] = Wv[i];
    }
    constexpr int RQ = KIN / 4;
    for (int i = t; i < 64 * RQ; i += 256) {
        int r = i / RQ, c = (i % RQ) * 4;
        int n = base + r;
        float4 v = make_float4(0.f, 0.f, 0.f, 0.f);
        if (n < N_NODES) v = *(const float4*)(in + (size_t)n * KIN + c);
        float* dp = rows + r * (KIN + 1) + c;
        dp[0] = v.x; dp[1] = v.y; dp[2] = v.z; dp[3] = v.w;
    }
    __syncthreads();
    int tr = t >> 4, tc = t & 15;
    float acc[4][4] = {};
    const float4* Wsv = (const float4*)Ws;
#pragma unroll 8
    for (int k = 0; k < KIN; ++k) {
        float4 w = Wsv[k * 16 + tc];
        float rv[4];
#pragma unroll
        for (int i = 0; i < 4; ++i) rv[i] = rows[(tr * 4 + i) * (KIN + 1) + k];
#pragma unroll
        for (int i = 0; i < 4; ++i) {
            acc[i][0] = fmaf(rv[i], w.x, acc[i][0]);
            acc[i][1] = fmaf(rv[i], w.y, acc[i][1]);
            acc[i][2] = fmaf(rv[i], w.z, acc[i][2]);
            acc[i][3] = fmaf(rv[i], w.w, acc[i][3]);
        }
    }
    int j0 = tc * 4;
#pragma unroll
    for (int i = 0; i < 4; ++i) {
        int n = base + tr * 4 + i;
        if (n < N_NODES) {
            ushort4 ov;
            ov.x = f2bf(acc[i][0]); ov.y = f2bf(acc[i][1]);
            ov.z = f2bf(acc[i][2]); ov.w = f2bf(acc[i][3]);
            *(ushort4*)(outB + (size_t)n * 64 + j0) = ov;
        }
    }
    if (MODE == 1) {
        float s0[4], s1[4];
#pragma unroll
        for (int i = 0; i < 4; ++i) {
            float pes = 0.f, ped = 0.f;
#pragma unroll
            for (int q = 0; q < 4; ++q) {
                pes = fmaf(acc[i][q], a_s[j0 + q], pes);
                ped = fmaf(acc[i][q], a_d[j0 + q], ped);
            }
            pes += __shfl_xor(pes, 1, 64);
            ped += __shfl_xor(ped, 1, 64);
            s0[i] = pes; s1[i] = ped;
        }
        if ((tc & 1) == 0) {
            int h = tc >> 1;
#pragma unroll
            for (int i = 0; i < 4; ++i) {
                int n = base + tr * 4 + i;
                if (n < N_NODES) {
                    es[n * NH + h] = s0[i];
                    ed[n * NH + h] = s1[i];
                }
            }
        }
    }
}

// ---------------------------------------------------------------------------
// Dual node GEMM (shared fp32 input, two weight mats, bf16 outputs).
// ---------------------------------------------------------------------------
__global__ __launch_bounds__(256)
void gemm_dual(const float* __restrict__ in, const float* __restrict__ W0,
               const float* __restrict__ W1,
               bfu* __restrict__ out0, bfu* __restrict__ out1)
{
    __shared__ float Ws[2 * 64 * 64];
    __shared__ float rows[64 * 65];
    int t = threadIdx.x;
    int base = blockIdx.x * 64;
    {
        const float4* W0v = (const float4*)W0;
        const float4* W1v = (const float4*)W1;
        float4* Wsv = (float4*)Ws;
        for (int i = t; i < 1024; i += 256) { Wsv[i] = W0v[i]; Wsv[1024 + i] = W1v[i]; }
    }
    for (int i = t; i < 64 * 16; i += 256) {
        int r = i / 16, c = (i % 16) * 4;
        int n = base + r;
        float4 v = make_float4(0.f, 0.f, 0.f, 0.f);
        if (n < N_NODES) v = *(const float4*)(in + (size_t)n * 64 + c);
        float* dp = rows + r * 65 + c;
        dp[0] = v.x; dp[1] = v.y; dp[2] = v.z; dp[3] = v.w;
    }
    __syncthreads();
    int tr = t >> 4, tc = t & 15;
    float a0[4][4] = {}, a1[4][4] = {};
    const float4* Wsv = (const float4*)Ws;
#pragma unroll 4
    for (int k = 0; k < 64; ++k) {
        float4 w0 = Wsv[k * 16 + tc];
        float4 w1 = Wsv[1024 + k * 16 + tc];
        float rv[4];
#pragma unroll
        for (int i = 0; i < 4; ++i) rv[i] = rows[(tr * 4 + i) * 65 + k];
#pragma unroll
        for (int i = 0; i < 4; ++i) {
            a0[i][0] = fmaf(rv[i], w0.x, a0[i][0]);
            a0[i][1] = fmaf(rv[i], w0.y, a0[i][1]);
            a0[i][2] = fmaf(rv[i], w0.z, a0[i][2]);
            a0[i][3] = fmaf(rv[i], w0.w, a0[i][3]);
            a1[i][0] = fmaf(rv[i], w1.x, a1[i][0]);
            a1[i][1] = fmaf(rv[i], w1.y, a1[i][1]);
            a1[i][2] = fmaf(rv[i], w1.z, a1[i][2]);
            a1[i][3] = fmaf(rv[i], w1.w, a1[i][3]);
        }
    }
    int j0 = tc * 4;
#pragma unroll
    for (int i = 0; i < 4; ++i) {
        int n = base + tr * 4 + i;
        if (n >= N_NODES) continue;
        ushort4 o0, o1;
        o0.x = f2bf(a0[i][0]); o0.y = f2bf(a0[i][1]);
        o0.z = f2bf(a0[i][2]); o0.w = f2bf(a0[i][3]);
        o1.x = f2bf(a1[i][0]); o1.y = f2bf(a1[i][1]);
        o1.z = f2bf(a1[i][2]); o1.w = f2bf(a1[i][3]);
        *(ushort4*)(out0 + (size_t)n * 64 + j0) = o0;
        *(ushort4*)(out1 + (size_t)n * 64 + j0) = o1;
    }
}

// ---------------------------------------------------------------------------
// CSR build: histogram -> scan -> scatter (+ dst array)
// ---------------------------------------------------------------------------
__global__ void csr_hist(const int* __restrict__ ei, int* __restrict__ cnt)
{
    int e = blockIdx.x * 256 + threadIdx.x;
    if (e >= E_EDGES) return;
    atomicAdd(&cnt[ei[E_EDGES + e]], 1);
}

__global__ void csr_scan1(const int* __restrict__ cnt, int* __restrict__ offs,
                          int* __restrict__ bsum)
{
    __shared__ int tmp[256];
    int t = threadIdx.x;
    int i = blockIdx.x * 256 + t;
    int v = (i < N_NODES) ? cnt[i] + 1 : 0;
    tmp[t] = v; __syncthreads();
#pragma unroll
    for (int o = 1; o < 256; o <<= 1) {
        int a = (t >= o) ? tmp[t - o] : 0;
        __syncthreads();
        tmp[t] += a;
        __syncthreads();
    }
    if (i < N_NODES) offs[i] = tmp[t] - v;
    if (t == 255) bsum[blockIdx.x] = tmp[255];
}

__global__ void csr_scan2(int* __restrict__ bsum)
{
    __shared__ int tmp[512];
    int t = threadIdx.x;
    int v = (t < NSCAN_BLK) ? bsum[t] : 0;
    tmp[t] = v; __syncthreads();
#pragma unroll
    for (int o = 1; o < 512; o <<= 1) {
        int a = (t >= o) ? tmp[t - o] : 0;
        __syncthreads();
        tmp[t] += a;
        __syncthreads();
    }
    if (t < NSCAN_BLK) bsum[t] = tmp[t] - v;
}

__global__ void csr_scan3(int* __restrict__ offs, const int* __restrict__ bsum,
                          int* __restrict__ cursor)
{
    int i = blockIdx.x * 256 + threadIdx.x;
    if (i < N_NODES) {
        int v = offs[i] + bsum[blockIdx.x];
        offs[i] = v;
        cursor[i] = v;
    }
    if (i == 0) offs[N_NODES] = E2;
}

__global__ void csr_scatter(const int* __restrict__ ei, int* __restrict__ cursor,
                            int* __restrict__ csr, int* __restrict__ csrd)
{
    int e = blockIdx.x * 256 + threadIdx.x;
    if (e >= E2) return;
    int d, tag;
    if (e < E_EDGES) { int s = ei[e]; d = ei[E_EDGES + e]; tag = s; }
    else             { d = e - E_EDGES; tag = d | SELF_FLAG; }
    int pos = atomicAdd(&cursor[d], 1);
    csr[pos] = tag;
    csrd[pos] = d;
}

// ---------------------------------------------------------------------------
// Fused GAT aggregate: wave per dst node; 4 edge-slots x 16 feature-lanes.
// Single pass (no segment-max; logits O(1)). bf16 gather, fp32 accumulate.
// WRITEBF: also emit bf16 copy of the output row (H table for GCN gather).
// ---------------------------------------------------------------------------
template<int ELU, int WRITEBF>
__global__ void gat_aggregate4(const int* __restrict__ offs, const int* __restrict__ csr,
                               const float* __restrict__ es, const float* __restrict__ ed,
                               const bfu* __restrict__ hsrcB, const float* __restrict__ bias,
                               float* __restrict__ out, bfu* __restrict__ outB)
{
    int n = blockIdx.x * 4 + (threadIdx.x >> 6);
    int lane = threadIdx.x & 63;
    if (n >= N_NODES) return;
    int g  = lane >> 4;        // edge slot 0..3
    int fl = lane & 15;        // feature chunk: features fl*4 .. fl*4+3
    int h  = fl >> 1;          // head
    int beg = offs[n], end = offs[n + 1];
    float edv = ed[n * NH + h];
    float den = 0.f;
    float4 acc = make_float4(0.f, 0.f, 0.f, 0.f);
    for (int p = beg + g; p < end; p += 4) {
        int s = csr[p] & SRC_MASK;
        float l = lrelu(es[s * NH + h] + edv);
        float ex = __expf(l);
        den += ex;
        ushort4 rb = *(const ushort4*)(hsrcB + (size_t)s * HD + fl * 4);
        acc.x = fmaf(bf2f(rb.x), ex, acc.x);
        acc.y = fmaf(bf2f(rb.y), ex, acc.y);
        acc.z = fmaf(bf2f(rb.z), ex, acc.z);
        acc.w = fmaf(bf2f(rb.w), ex, acc.w);
    }
#pragma unroll
    for (int o = 16; o <= 32; o <<= 1) {
        den   += __shfl_xor(den,   o, 64);
        acc.x += __shfl_xor(acc.x, o, 64);
        acc.y += __shfl_xor(acc.y, o, 64);
        acc.z += __shfl_xor(acc.z, o, 64);
        acc.w += __shfl_xor(acc.w, o, 64);
    }
    if (g == 0) {
        float inv = 1.f / (den + 1e-16f);
        float4 bv = *(const float4*)(bias + fl * 4);
        float v0 = acc.x * inv + bv.x;
        float v1 = acc.y * inv + bv.y;
        float v2 = acc.z * inv + bv.z;
        float v3 = acc.w * inv + bv.w;
        if (ELU) {
            v0 = v0 > 0.f ? v0 : (__expf(v0) - 1.f);
            v1 = v1 > 0.f ? v1 : (__expf(v1) - 1.f);
            v2 = v2 > 0.f ? v2 : (__expf(v2) - 1.f);
            v3 = v3 > 0.f ? v3 : (__expf(v3) - 1.f);
        }
        *(float4*)(out + (size_t)n * HD + fl * 4) = make_float4(v0, v1, v2, v3);
        if (WRITEBF) {
            ushort4 ov;
            ov.x = f2bf(v0); ov.y = f2bf(v1); ov.z = f2bf(v2); ov.w = f2bf(v3);
            *(ushort4*)(outB + (size_t)n * HD + fl * 4) = ov;
        }
    }
}

// ---------------------------------------------------------------------------
// node attention, tiled: 64 nodes/block -> packed float2 (alpha_c, alpha_t)
// ---------------------------------------------------------------------------
__global__ __launch_bounds__(256)
void node_att_tile(const float* __restrict__ H, const float* __restrict__ w1,
                   const float* __restrict__ b1, const float* __restrict__ w2,
                   const float* __restrict__ b2, float2* __restrict__ al2)
{
    __shared__ float w1s[64 * 32];
    __shared__ float w2s[64];
    __shared__ float rows[64 * 65];
    int t = threadIdx.x;
    int base = blockIdx.x * 64;
    {
        const float4* w1v = (const float4*)w1;
        float4* dst = (float4*)w1s;
        for (int i = t; i < 512; i += 256) dst[i] = w1v[i];
    }
    if (t < 64) w2s[t] = w2[t];
    for (int i = t; i < 64 * 16; i += 256) {
        int r = i >> 4, c = (i & 15) * 4;
        int n = base + r;
        float4 v = make_float4(0.f, 0.f, 0.f, 0.f);
        if (n < N_NODES) v = *(const float4*)(H + (size_t)n * 64 + c);
        float* dp = rows + r * 65 + c;
        dp[0] = v.x; dp[1] = v.y; dp[2] = v.z; dp[3] = v.w;
    }
    __syncthreads();
    int tr = t >> 3;
    int tc = t & 7;
    float4 bv = *(const float4*)(b1 + tc * 4);
    float4 acc0 = bv, acc1 = bv;
    const float4* w1sv = (const float4*)w1s;
#pragma unroll 8
    for (int k = 0; k < 64; ++k) {
        float4 w = w1sv[k * 8 + tc];
        float r0 = rows[tr * 65 + k];
        float r1 = rows[(tr + 32) * 65 + k];
        acc0.x = fmaf(r0, w.x, acc0.x); acc0.y = fmaf(r0, w.y, acc0.y);
        acc0.z = fmaf(r0, w.z, acc0.z); acc0.w = fmaf(r0, w.w, acc0.w);
        acc1.x = fmaf(r1, w.x, acc1.x); acc1.y = fmaf(r1, w.y, acc1.y);
        acc1.z = fmaf(r1, w.z, acc1.z); acc1.w = fmaf(r1, w.w, acc1.w);
    }
    float z00 = 0.f, z01 = 0.f, z10 = 0.f, z11 = 0.f;
    float h0, w20, w21;
    int j0 = tc * 4;
#pragma unroll
    for (int q = 0; q < 4; ++q) {
        float a0q = q == 0 ? acc0.x : q == 1 ? acc0.y : q == 2 ? acc0.z : acc0.w;
        float a1q = q == 0 ? acc1.x : q == 1 ? acc1.y : q == 2 ? acc1.z : acc1.w;
        w20 = w2s[(j0 + q) * 2]; w21 = w2s[(j0 + q) * 2 + 1];
        h0 = fmaxf(a0q, 0.f);
        z00 = fmaf(h0, w20, z00); z01 = fmaf(h0, w21, z01);
        h0 = fmaxf(a1q, 0.f);
        z10 = fmaf(h0, w20, z10); z11 = fmaf(h0, w21, z11);
    }
#pragma unroll
    for (int o = 1; o < 8; o <<= 1) {
        z00 += __shfl_xor(z00, o, 64); z01 += __shfl_xor(z01, o, 64);
        z10 += __shfl_xor(z10, o, 64); z11 += __shfl_xor(z11, o, 64);
    }
    if (tc == 0) {
        int n0 = base + tr, n1 = base + tr + 32;
        if (n0 < N_NODES) {
            float zz0 = z00 + b2[0], zz1 = z01 + b2[1];
            float mx = fmaxf(zz0, zz1);
            float e0 = __expf(zz0 - mx), e1 = __expf(zz1 - mx);
            float ss = e0 + e1;
            al2[n0] = make_float2(e0 / ss, e1 / ss);
        }
        if (n1 < N_NODES) {
            float zz0 = z10 + b2[0], zz1 = z11 + b2[1];
            float mx = fmaxf(zz0, zz1);
            float e0 = __expf(zz0 - mx), e1 = __expf(zz1 - mx);
            float ss = e0 + e1;
            al2[n1] = make_float2(e0 / ss, e1 / ss);
        }
    }
}

// ---------------------------------------------------------------------------
// edge attention, flat over CSR: 8 lanes/edge, bf16 P1/P2 gather. NO atomics.
// ---------------------------------------------------------------------------
__global__ __launch_bounds__(256)
void edge_att_flat(const int* __restrict__ csr, const int* __restrict__ csrd,
                   const bfu* __restrict__ P1b, const bfu* __restrict__ P2b,
                   const float* __restrict__ b1, const float* __restrict__ w2,
                   const float* __restrict__ b2,
                   float* __restrict__ bc, float* __restrict__ bt)
{
    int lane = threadIdx.x & 63;
    int sg = lane >> 3, q = lane & 7;
    int p = (blockIdx.x * 4 + (threadIdx.x >> 6)) * 8 + sg;
    if (p >= E2) return;
    int sv = csr[p];
    if (sv & SELF_FLAG) return;
    int d = csrd[p];
    uint4 U1 = *(const uint4*)(P1b + (size_t)sv * 64 + q * 8);
    uint4 U2 = *(const uint4*)(P2b + (size_t)d  * 64 + q * 8);
    const float4* pb = (const float4*)(b1 + q * 8);
    const float4* pw = (const float4*)(w2 + q * 16);
    float4 c0 = pb[0], c1 = pb[1];
    float4 w0 = pw[0], w1v = pw[1], w2v = pw[2], w3v = pw[3];
    float h0 = fmaxf(bflo(U1.x) + bflo(U2.x) + c0.x, 0.f);
    float h1 = fmaxf(bfhi(U1.x) + bfhi(U2.x) + c0.y, 0.f);
    float h2 = fmaxf(bflo(U1.y) + bflo(U2.y) + c0.z, 0.f);
    float h3 = fmaxf(bfhi(U1.y) + bfhi(U2.y) + c0.w, 0.f);
    float h4 = fmaxf(bflo(U1.z) + bflo(U2.z) + c1.x, 0.f);
    float h5 = fmaxf(bfhi(U1.z) + bfhi(U2.z) + c1.y, 0.f);
    float h6 = fmaxf(bflo(U1.w) + bflo(U2.w) + c1.z, 0.f);
    float h7 = fmaxf(bfhi(U1.w) + bfhi(U2.w) + c1.w, 0.f);
    float z0 = h0 * w0.x + h1 * w0.z + h2 * w1v.x + h3 * w1v.z
             + h4 * w2v.x + h5 * w2v.z + h6 * w3v.x + h7 * w3v.z;
    float z1 = h0 * w0.y + h1 * w0.w + h2 * w1v.y + h3 * w1v.w
             + h4 * w2v.y + h5 * w2v.w + h6 * w3v.y + h7 * w3v.w;
    z0 += __shfl_xor(z0, 1, 64); z1 += __shfl_xor(z1, 1, 64);
    z0 += __shfl_xor(z0, 2, 64); z1 += __shfl_xor(z1, 2, 64);
    z0 += __shfl_xor(z0, 4, 64); z1 += __shfl_xor(z1, 4, 64);
    if (q == 0) {
        z0 += b2[0]; z1 += b2[1];
        float mx = fmaxf(z0, z1);
        float e0 = __expf(z0 - mx), e1 = __expf(z1 - mx);
        float ss = e0 + e1;
        bc[p] = e0 / ss;
        bt[p] = e1 / ss;
    }
}

// ---------------------------------------------------------------------------
// GCN: per-node degree gather (no atomics) -> dis; then per-edge norms
// ---------------------------------------------------------------------------
__global__ void gcn_deg_dis(const int* __restrict__ offs, const int* __restrict__ csr,
                            const float* __restrict__ bc, const float* __restrict__ bt,
                            float* __restrict__ disc, float* __restrict__ dist)
{
    int n = blockIdx.x * 256 + threadIdx.x;
    if (n >= N_NODES) return;
    int beg = offs[n], end = offs[n + 1];
    float dc = 0.f, dt = 0.f;
    for (int p = beg; p < end; ++p) {
        if (csr[p] & SELF_FLAG) { dc += 1.f; dt += 1.f; }
        else { dc += bc[p]; dt += bt[p]; }
    }
    disc[n] = rsqrtf(fmaxf(dc, 1e-20f));   // deg >= 1 (self loop)
    dist[n] = rsqrtf(fmaxf(dt, 1e-20f));
}

__global__ void gcn_norm(const int* __restrict__ csr, const int* __restrict__ csrd,
                         const float* __restrict__ disc, const float* __restrict__ dist,
                         float* __restrict__ bc, float* __restrict__ bt)
{
    int p = blockIdx.x * 256 + threadIdx.x;
    if (p >= E2) return;
    int sv = csr[p];
    int s = sv & SRC_MASK;
    int d = csrd[p];
    float wc, wt;
    if (sv & SELF_FLAG) { wc = 1.f; wt = 1.f; }
    else { wc = bc[p]; wt = bt[p]; }
    bc[p] = disc[s] * wc * disc[d];
    bt[p] = dist[s] * wt * dist[d];
}

// ---------------------------------------------------------------------------
// GCN aggregate with SHARED bf16 H table: agg_c[d] = sum nrmC*alpha_c[s]*H[s]
// (the gc_w GEMM is commuted past the segment sum -> applied in readout_head)
// ---------------------------------------------------------------------------
__global__ void gcn_aggregate_shared(const int* __restrict__ offs, const int* __restrict__ csr,
                                     const bfu* __restrict__ HB, const float2* __restrict__ al2,
                                     const float* __restrict__ nrmC, const float* __restrict__ nrmT,
                                     float* __restrict__ outC, float* __restrict__ outT)
{
    int n = blockIdx.x * 4 + (threadIdx.x >> 6);
    int lane = threadIdx.x & 63;
    if (n >= N_NODES) return;
    int g  = lane >> 4;
    int fl = lane & 15;
    int beg = offs[n], end = offs[n + 1];
    float4 a1 = make_float4(0.f, 0.f, 0.f, 0.f);
    float4 a2 = make_float4(0.f, 0.f, 0.f, 0.f);
    for (int p = beg + g; p < end; p += 4) {
        int s = csr[p] & SRC_MASK;
        float2 al = al2[s];
        float wc = nrmC[p] * al.x, wt = nrmT[p] * al.y;
        ushort4 rb = *(const ushort4*)(HB + (size_t)s * HD + fl * 4);
        float r0 = bf2f(rb.x), r1 = bf2f(rb.y), r2 = bf2f(rb.z), r3 = bf2f(rb.w);
        a1.x = fmaf(r0, wc, a1.x); a1.y = fmaf(r1, wc, a1.y);
        a1.z = fmaf(r2, wc, a1.z); a1.w = fmaf(r3, wc, a1.w);
        a2.x = fmaf(r0, wt, a2.x); a2.y = fmaf(r1, wt, a2.y);
        a2.z = fmaf(r2, wt, a2.z); a2.w = fmaf(r3, wt, a2.w);
    }
#pragma unroll
    for (int o = 16; o <= 32; o <<= 1) {
        a1.x += __shfl_xor(a1.x, o, 64); a1.y += __shfl_xor(a1.y, o, 64);
        a1.z += __shfl_xor(a1.z, o, 64); a1.w += __shfl_xor(a1.w, o, 64);
        a2.x += __shfl_xor(a2.x, o, 64); a2.y += __shfl_xor(a2.y, o, 64);
        a2.z += __shfl_xor(a2.z, o, 64); a2.w += __shfl_xor(a2.w, o, 64);
    }
    if (g == 0) {
        *(float4*)(outC + (size_t)n * HD + fl * 4) = a1;
        *(float4*)(outT + (size_t)n * HD + fl * 4) = a2;
    }
}

// ---------------------------------------------------------------------------
// weight prep: Wp = gw @ rw (64x64), bp = gb @ rw + rb
// ---------------------------------------------------------------------------
__global__ void weight_prep(const float* __restrict__ gw, const float* __restrict__ gb,
                            const float* __restrict__ rw, const float* __restrict__ rb,
                            float* __restrict__ Wp, float* __restrict__ bp)
{
    __shared__ float A[4096], B[4096];
    int t = threadIdx.x;
    {
        const float4* ga = (const float4*)gw;
        const float4* rA = (const float4*)rw;
        float4* dA = (float4*)A; float4* dB = (float4*)B;
        for (int i = t; i < 1024; i += 256) { dA[i] = ga[i]; dB[i] = rA[i]; }
    }
    __syncthreads();
    for (int e = t * 16; e < t * 16 + 16; ++e) {
        int k = e >> 6, j = e & 63;
        float acc = 0.f;
#pragma unroll 8
        for (int m = 0; m < 64; ++m) acc = fmaf(A[k * 64 + m], B[m * 64 + j], acc);
        Wp[e] = acc;
    }
    if (t < 64) {
        float acc = rb[t];
#pragma unroll 8
        for (int m = 0; m < 64; ++m) acc = fmaf(gb[m], B[m * 64 + t], acc);
        bp[t] = acc;
    }
}

// ---------------------------------------------------------------------------
// merged readout + heads: one block per graph. Binary-search the node range
// in sorted `batch`, coalesced float4 accumulate, LDS reduce, then all heads.
// hGc = S_aggc @ Wcp + cnt*bcp  (Wcp = gc_w@rc_w, bcp = gc_b@rc_w + rc_b)
// ---------------------------------------------------------------------------
__global__ __launch_bounds__(256)
void readout_head(const float* __restrict__ Gc, const float* __restrict__ Gt,
                  const int* __restrict__ batch,
                  const float* __restrict__ Wcp, const float* __restrict__ bcp,
                  const float* __restrict__ Wtp, const float* __restrict__ btp,
                  const float* __restrict__ cc_w1, const float* __restrict__ cc_b1,
                  const float* __restrict__ cc_w2, const float* __restrict__ cc_b2,
                  const float* __restrict__ ct_w1, const float* __restrict__ ct_b1,
                  const float* __restrict__ ct_w2, const float* __restrict__ ct_b2,
                  const float* __restrict__ cm_w1, const float* __restrict__ cm_b1,
                  const float* __restrict__ cm_w2, const float* __restrict__ cm_b2,
                  float* __restrict__ out)
{
    int g = blockIdx.x;
    int t = threadIdx.x;
    // binary search (all threads, identical -> uniform)
    int lo, hi;
    {
        int l = 0, r = N_NODES;
        while (l < r) { int m = (l + r) >> 1; if (batch[m] < g) l = m + 1; else r = m; }
        lo = l;
        r = N_NODES;
        while (l < r) { int m = (l + r) >> 1; if (batch[m] < g + 1) l = m + 1; else r = m; }
        hi = l;
    }
    int slot = t >> 4, fl = t & 15;
    float4 a1 = make_float4(0.f, 0.f, 0.f, 0.f);
    float4 a2 = make_float4(0.f, 0.f, 0.f, 0.f);
    const float4* Gc4 = (const float4*)Gc;
    const float4* Gt4 = (const float4*)Gt;
    int r = lo + slot;
    for (; r + 16 < hi; r += 32) {
        float4 u0 = Gc4[(size_t)r * 16 + fl];
        float4 v0 = Gt4[(size_t)r * 16 + fl];
        float4 u1 = Gc4[(size_t)(r + 16) * 16 + fl];
        float4 v1 = Gt4[(size_t)(r + 16) * 16 + fl];
        a1.x += u0.x + u1.x; a1.y += u0.y + u1.y; a1.z += u0.z + u1.z; a1.w += u0.w + u1.w;
        a2.x += v0.x + v1.x; a2.y += v0.y + v1.y; a2.z += v0.z + v1.z; a2.w += v0.w + v1.w;
    }
    if (r < hi) {
        float4 u0 = Gc4[(size_t)r * 16 + fl];
        float4 v0 = Gt4[(size_t)r * 16 + fl];
        a1.x += u0.x; a1.y += u0.y; a1.z += u0.z; a1.w += u0.w;
        a2.x += v0.x; a2.y += v0.y; a2.z += v0.z; a2.w += v0.w;
    }
    __shared__ float redc[16 * 64], redt[16 * 64];
    __shared__ float scl[64], stl[64], hgc[64], hgt[64], hid[64];
    *(float4*)(redc + slot * 64 + fl * 4) = a1;
    *(float4*)(redt + slot * 64 + fl * 4) = a2;
    __syncthreads();
    if (t < 64) {
        float sc = 0.f, st = 0.f;
#pragma unroll
        for (int s = 0; s < 16; ++s) { sc += redc[s * 64 + t]; st += redt[s * 64 + t]; }
        scl[t] = sc; stl[t] = st;
    }
    __syncthreads();
    float c = (float)(hi - lo);
    if (t < 64) {
        float a = c * bcp[t], b = c * btp[t];
#pragma unroll 8
        for (int k = 0; k < 64; ++k) {
            a = fmaf(scl[k], Wcp[k * 64 + t], a);
            b = fmaf(stl[k], Wtp[k * 64 + t], b);
        }
        hgc[t] = a; hgt[t] = b;
        out[3840 + g * 64 + t]  = a;
        out[12032 + g * 64 + t] = b;
    }
    __syncthreads();
    if (t < 32) {
        float a = cc_b1[t];
#pragma unroll 8
        for (int k = 0; k < 64; ++k) a = fmaf(hgc[k], cc_w1[k * 32 + t], a);
        hid[t] = fmaxf(a, 0.f);
    }
    __syncthreads();
    if (t < NC) {
        float a = cc_b2[t];
#pragma unroll
        for (int k = 0; k < 32; ++k) a = fmaf(hid[k], cc_w2[k * NC + t], a);
        out[g * NC + t] = a;
    }
    __syncthreads();
    if (t < 32) {
        float a = ct_b1[t];
#pragma unroll 8
        for (int k = 0; k < 64; ++k) a = fmaf(hgt[k], ct_w1[k * 32 + t], a);
        hid[t] = fmaxf(a, 0.f);
    }
    __syncthreads();
    if (t < NC) {
        float a = ct_b2[t];
#pragma unroll
        for (int k = 0; k < 32; ++k) a = fmaf(hid[k], ct_w2[k * NC + t], a);
        out[1280 + g * NC + t] = a;
    }
    __syncthreads();
    if (t < 64) {
        float a = cm_b1[t];
#pragma unroll 8
        for (int k = 0; k < 64; ++k) {
            a = fmaf(hgc[k], cm_w1[k * 64 + t], a);
            a = fmaf(hgt[k], cm_w1[(64 + k) * 64 + t], a);
        }
        hid[t] = fmaxf(a, 0.f);
    }
    __syncthreads();
    if (t < NC) {
        float a = cm_b2[t];
#pragma unroll 8
        for (int k = 0; k < 64; ++k) a = fmaf(hid[k], cm_w2[k * NC + t], a);
        out[2560 + g * NC + t] = a;
    }
}

// ---------------------------------------------------------------------------
extern "C" void kernel_launch(void* const* d_in, const int* in_sizes, int n_in,
                              void* d_out, int out_size, void* d_ws, size_t ws_size,
                              hipStream_t stream)
{
    const float* x     = (const float*)d_in[0];
    const int*   ei    = (const int*)d_in[1];
    const int*   batch = (const int*)d_in[2];
    const float* W1    = (const float*)d_in[3];
    const float* as1   = (const float*)d_in[4];
    const float* ad1   = (const float*)d_in[5];
    const float* b1    = (const float*)d_in[6];
    const float* W2    = (const float*)d_in[7];
    const float* as2   = (const float*)d_in[8];
    const float* ad2   = (const float*)d_in[9];
    const float* b2    = (const float*)d_in[10];
    const float* na_w1 = (const float*)d_in[11];
    const float* na_b1 = (const float*)d_in[12];
    const float* na_w2 = (const float*)d_in[13];
    const float* na_b2 = (const float*)d_in[14];
    const float* ea_w1 = (const float*)d_in[15];
    const float* ea_b1 = (const float*)d_in[16];
    const float* ea_w2 = (const float*)d_in[17];
    const float* ea_b2 = (const float*)d_in[18];
    const float* gc_w  = (const float*)d_in[19];
    const float* gc_b  = (const float*)d_in[20];
    const float* gt_w  = (const float*)d_in[21];
    const float* gt_b  = (const float*)d_in[22];
    const float* rc_w  = (const float*)d_in[23];
    const float* rc_b  = (const float*)d_in[24];
    const float* rt_w  = (const float*)d_in[25];
    const float* rt_b  = (const float*)d_in[26];
    const float* cc_w1 = (const float*)d_in[27];
    const float* cc_b1 = (const float*)d_in[28];
    const float* cc_w2 = (const float*)d_in[29];
    const float* cc_b2 = (const float*)d_in[30];
    const float* ct_w1 = (const float*)d_in[31];
    const float* ct_b1 = (const float*)d_in[32];
    const float* ct_w2 = (const float*)d_in[33];
    const float* ct_b2 = (const float*)d_in[34];
    const float* cm_w1 = (const float*)d_in[35];
    const float* cm_b1 = (const float*)d_in[36];
    const float* cm_w2 = (const float*)d_in[37];
    const float* cm_b2 = (const float*)d_in[38];
    float* out = (float*)d_out;

    float* ws = (float*)d_ws;
    size_t o = 0;
    const size_t nf = (size_t)N_NODES * HD;
    float* T1   = ws + o; o += nf;             // H1 / agg_c
    float* T2   = ws + o; o += nf;             // H (fp32)
    float* es   = ws + o; o += (size_t)N_NODES * NH;
    float* ed   = ws + o; o += (size_t)N_NODES * NH;
    float2* al2 = (float2*)(ws + o); o += (size_t)N_NODES * 2;
    float* bc   = ws + o; o += E2;             // beta_c -> norm_c (in place)
    float* bt   = ws + o; o += E2;             // beta_t -> norm_t (in place)
    float* degc = ws + o; o += N_NODES;        // dis_c
    float* degt = ws + o; o += N_NODES;
    bfu* B0     = (bfu*)(ws + o); o += nf / 2; // bf16 gather table (also agg_t region)
    bfu* B1     = (bfu*)(ws + o); o += nf / 2;
    bfu* B2     = (bfu*)(ws + o); o += nf / 2; // bf16 H table
    int* csr    = (int*)(ws + o); o += E2;
    int* csrd   = (int*)(ws + o); o += E2;
    int* offs   = (int*)(ws + o); o += N_NODES + 1;
    float* Wcp  = ws + o; o += 4096;
    float* Wtp  = ws + o; o += 4096;
    float* bcp  = ws + o; o += 64;
    float* btp  = ws + o; o += 64;
    // CSR-build temporaries alias buffers written later:
    int* cnt    = (int*)bc;
    int* cursor = (int*)bt;
    int* bsum   = (int*)degc;
    float* aggT = (float*)B0;   // agg_t overwrites B0+B1 region (nf floats) after edge att

    const int NW_BLKS = N_NODES / 4;             // 25000
    const int NT_BLKS = (N_NODES + 255) / 256;   // 391
    const int E_BLKS  = (E2 + 255) / 256;        // 3516
    const int EF_BLKS = (E2 + 31) / 32;          // 28125

    // ---------------- CSR build ----------------
    hipMemsetAsync(cnt, 0, (size_t)N_NODES * 4, stream);
    csr_hist<<<(E_EDGES + 255) / 256, 256, 0, stream>>>(ei, cnt);
    csr_scan1<<<NSCAN_BLK, 256, 0, stream>>>(cnt, offs, bsum);
    csr_scan2<<<1, 512, 0, stream>>>(bsum);
    csr_scan3<<<NSCAN_BLK, 256, 0, stream>>>(offs, bsum, cursor);
    csr_scatter<<<E_BLKS, 256, 0, stream>>>(ei, cursor, csr, csrd);

    // ---------------- GAT layer 1 ----------------
    gemm_tile<FIN, 1><<<NBLK64, 256, 0, stream>>>(x, W1, B0, as1, ad1, es, ed);
    gat_aggregate4<1, 0><<<NW_BLKS, 256, 0, stream>>>(offs, csr, es, ed, B0, b1, T1, nullptr);

    // ---------------- GAT layer 2 ----------------
    gemm_tile<64, 1><<<NBLK64, 256, 0, stream>>>(T1, W2, B0, as2, ad2, es, ed);
    gat_aggregate4<0, 1><<<NW_BLKS, 256, 0, stream>>>(offs, csr, es, ed, B0, b2, T2, B2);

    // ---------------- node attention (alpha pair) ----------------
    node_att_tile<<<NBLK64, 256, 0, stream>>>(T2, na_w1, na_b1, na_w2, na_b2, al2);

    // ---------------- edge attention (P1 -> B0, P2 -> B1, bf16) -------------
    gemm_dual<<<NBLK64, 256, 0, stream>>>(T2, ea_w1, ea_w1 + 64 * 64, B0, B1);
    edge_att_flat<<<EF_BLKS, 256, 0, stream>>>(csr, csrd, B0, B1, ea_b1, ea_w2, ea_b2, bc, bt);

    // ---------------- GCN norm (bc/bt -> per-edge norms in place) -----------
    gcn_deg_dis<<<NT_BLKS, 256, 0, stream>>>(offs, csr, bc, bt, degc, degt);
    gcn_norm<<<E_BLKS, 256, 0, stream>>>(csr, csrd, degc, degt, bc, bt);

    // ---------------- weight prep (commuted GCN+readout weights) ------------
    weight_prep<<<1, 256, 0, stream>>>(gc_w, gc_b, rc_w, rc_b, Wcp, bcp);
    weight_prep<<<1, 256, 0, stream>>>(gt_w, gt_b, rt_w, rt_b, Wtp, btp);

    // ---------------- GCN aggregate (shared H table) -------------------------
    gcn_aggregate_shared<<<NW_BLKS, 256, 0, stream>>>(offs, csr, B2, al2, bc, bt, T1, aggT);

    // ---------------- merged readout + heads --------------------------------
    readout_head<<<NG, 256, 0, stream>>>(T1, aggT, batch,
                                         Wcp, bcp, Wtp, btp,
                                         cc_w1, cc_b1, cc_w2, cc_b2,
                                         ct_w1, ct_b1, ct_w2, ct_b2,
                                         cm_w1, cm_b1, cm_w2, cm_b2, out);
    (void)in_sizes; (void)n_in; (void)out_size; (void)ws_size;
}

// Round 10
// 589.589 us; speedup vs baseline: 1.1632x; 1.0460x over previous
//
#include <hip/hip_runtime.h>
#include <hip/hip_bf16.h>

#define N_NODES 100000
#define E_EDGES 800000
#define E2 (E_EDGES + N_NODES)   // 900000 edges incl. self loops
#define FIN 128
#define HD 64
#define NH 8
#define NG 128
#define NC 10
#define SLOPE 0.2f
#define SELF_FLAG 0x40000000
#define SRC_MASK  0x3FFFFFFF
#define NSCAN_BLK 391            // ceil(N/256)
#define NBLK64 1563              // ceil(N/64)
#define GB 8                     // blocks per graph in fused gcn+readout

typedef unsigned short bfu;

__device__ __forceinline__ float lrelu(float x) { return x > 0.f ? x : SLOPE * x; }

__device__ __forceinline__ bfu f2bf(float f) {
    unsigned int u = __float_as_uint(f);
    u += 0x7FFFu + ((u >> 16) & 1u);          // round-to-nearest-even
    return (bfu)(u >> 16);
}
__device__ __forceinline__ float bf2f(bfu s) {
    return __uint_as_float(((unsigned int)s) << 16);
}
__device__ __forceinline__ float bflo(unsigned int u) { return __uint_as_float(u << 16); }
__device__ __forceinline__ float bfhi(unsigned int u) { return __uint_as_float(u & 0xFFFF0000u); }

// ---------------------------------------------------------------------------
// Tiled node GEMM: 64 nodes/block, thread = 4 nodes x 4 outputs.
// TIN = float or bfu (bf16 rows). Output table bf16. MODE 1: es/ed epilogue.
// ---------------------------------------------------------------------------
template<typename TIN, int KIN, int MODE>
__global__ __launch_bounds__(256)
void gemm_tile(const TIN* __restrict__ in, const float* __restrict__ W,
               bfu* __restrict__ outB,
               const float* __restrict__ a_s, const float* __restrict__ a_d,
               float* __restrict__ es, float* __restrict__ ed)
{
    __shared__ float Ws[KIN * 64];
    __shared__ float rows[64 * (KIN + 1)];
    int t = threadIdx.x;
    int base = blockIdx.x * 64;
    {
        const float4* Wv = (const float4*)W;
        float4* Wsv = (float4*)Ws;
        for (int i = t; i < KIN * 16; i += 256) Wsv[i] = Wv[i];
    }
    if constexpr (sizeof(TIN) == 4) {
        constexpr int RQ = KIN / 4;
        for (int i = t; i < 64 * RQ; i += 256) {
            int r = i / RQ, c = (i % RQ) * 4;
            int n = base + r;
            float4 v = make_float4(0.f, 0.f, 0.f, 0.f);
            if (n < N_NODES) v = *(const float4*)((const float*)in + (size_t)n * KIN + c);
            float* dp = rows + r * (KIN + 1) + c;
            dp[0] = v.x; dp[1] = v.y; dp[2] = v.z; dp[3] = v.w;
        }
    } else {
        constexpr int RQ = KIN / 8;
        for (int i = t; i < 64 * RQ; i += 256) {
            int r = i / RQ, c = (i % RQ) * 8;
            int n = base + r;
            uint4 v = make_uint4(0, 0, 0, 0);
            if (n < N_NODES) v = *(const uint4*)((const bfu*)in + (size_t)n * KIN + c);
            float* dp = rows + r * (KIN + 1) + c;
            dp[0] = bflo(v.x); dp[1] = bfhi(v.x);
            dp[2] = bflo(v.y); dp[3] = bfhi(v.y);
            dp[4] = bflo(v.z); dp[5] = bfhi(v.z);
            dp[6] = bflo(v.w); dp[7] = bfhi(v.w);
        }
    }
    __syncthreads();
    int tr = t >> 4, tc = t & 15;
    float acc[4][4] = {};
    const float4* Wsv = (const float4*)Ws;
#pragma unroll 8
    for (int k = 0; k < KIN; ++k) {
        float4 w = Wsv[k * 16 + tc];
        float rv[4];
#pragma unroll
        for (int i = 0; i < 4; ++i) rv[i] = rows[(tr * 4 + i) * (KIN + 1) + k];
#pragma unroll
        for (int i = 0; i < 4; ++i) {
            acc[i][0] = fmaf(rv[i], w.x, acc[i][0]);
            acc[i][1] = fmaf(rv[i], w.y, acc[i][1]);
            acc[i][2] = fmaf(rv[i], w.z, acc[i][2]);
            acc[i][3] = fmaf(rv[i], w.w, acc[i][3]);
        }
    }
    int j0 = tc * 4;
#pragma unroll
    for (int i = 0; i < 4; ++i) {
        int n = base + tr * 4 + i;
        if (n < N_NODES) {
            ushort4 ov;
            ov.x = f2bf(acc[i][0]); ov.y = f2bf(acc[i][1]);
            ov.z = f2bf(acc[i][2]); ov.w = f2bf(acc[i][3]);
            *(ushort4*)(outB + (size_t)n * 64 + j0) = ov;
        }
    }
    if (MODE == 1) {
        float s0[4], s1[4];
#pragma unroll
        for (int i = 0; i < 4; ++i) {
            float pes = 0.f, ped = 0.f;
#pragma unroll
            for (int q = 0; q < 4; ++q) {
                pes = fmaf(acc[i][q], a_s[j0 + q], pes);
                ped = fmaf(acc[i][q], a_d[j0 + q], ped);
            }
            pes += __shfl_xor(pes, 1, 64);
            ped += __shfl_xor(ped, 1, 64);
            s0[i] = pes; s1[i] = ped;
        }
        if ((tc & 1) == 0) {
            int h = tc >> 1;
#pragma unroll
            for (int i = 0; i < 4; ++i) {
                int n = base + tr * 4 + i;
                if (n < N_NODES) {
                    es[n * NH + h] = s0[i];
                    ed[n * NH + h] = s1[i];
                }
            }
        }
    }
}

// ---------------------------------------------------------------------------
// Dual node GEMM (bf16 input rows, two weight mats, bf16 outputs).
// ---------------------------------------------------------------------------
__global__ __launch_bounds__(256)
void gemm_dual(const bfu* __restrict__ in, const float* __restrict__ W0,
               const float* __restrict__ W1,
               bfu* __restrict__ out0, bfu* __restrict__ out1)
{
    __shared__ float Ws[2 * 64 * 64];
    __shared__ float rows[64 * 65];
    int t = threadIdx.x;
    int base = blockIdx.x * 64;
    {
        const float4* W0v = (const float4*)W0;
        const float4* W1v = (const float4*)W1;
        float4* Wsv = (float4*)Ws;
        for (int i = t; i < 1024; i += 256) { Wsv[i] = W0v[i]; Wsv[1024 + i] = W1v[i]; }
    }
    for (int i = t; i < 64 * 8; i += 256) {
        int r = i >> 3, c = (i & 7) * 8;
        int n = base + r;
        uint4 v = make_uint4(0, 0, 0, 0);
        if (n < N_NODES) v = *(const uint4*)(in + (size_t)n * 64 + c);
        float* dp = rows + r * 65 + c;
        dp[0] = bflo(v.x); dp[1] = bfhi(v.x);
        dp[2] = bflo(v.y); dp[3] = bfhi(v.y);
        dp[4] = bflo(v.z); dp[5] = bfhi(v.z);
        dp[6] = bflo(v.w); dp[7] = bfhi(v.w);
    }
    __syncthreads();
    int tr = t >> 4, tc = t & 15;
    float a0[4][4] = {}, a1[4][4] = {};
    const float4* Wsv = (const float4*)Ws;
#pragma unroll 4
    for (int k = 0; k < 64; ++k) {
        float4 w0 = Wsv[k * 16 + tc];
        float4 w1 = Wsv[1024 + k * 16 + tc];
        float rv[4];
#pragma unroll
        for (int i = 0; i < 4; ++i) rv[i] = rows[(tr * 4 + i) * 65 + k];
#pragma unroll
        for (int i = 0; i < 4; ++i) {
            a0[i][0] = fmaf(rv[i], w0.x, a0[i][0]);
            a0[i][1] = fmaf(rv[i], w0.y, a0[i][1]);
            a0[i][2] = fmaf(rv[i], w0.z, a0[i][2]);
            a0[i][3] = fmaf(rv[i], w0.w, a0[i][3]);
            a1[i][0] = fmaf(rv[i], w1.x, a1[i][0]);
            a1[i][1] = fmaf(rv[i], w1.y, a1[i][1]);
            a1[i][2] = fmaf(rv[i], w1.z, a1[i][2]);
            a1[i][3] = fmaf(rv[i], w1.w, a1[i][3]);
        }
    }
    int j0 = tc * 4;
#pragma unroll
    for (int i = 0; i < 4; ++i) {
        int n = base + tr * 4 + i;
        if (n >= N_NODES) continue;
        ushort4 o0, o1;
        o0.x = f2bf(a0[i][0]); o0.y = f2bf(a0[i][1]);
        o0.z = f2bf(a0[i][2]); o0.w = f2bf(a0[i][3]);
        o1.x = f2bf(a1[i][0]); o1.y = f2bf(a1[i][1]);
        o1.z = f2bf(a1[i][2]); o1.w = f2bf(a1[i][3]);
        *(ushort4*)(out0 + (size_t)n * 64 + j0) = o0;
        *(ushort4*)(out1 + (size_t)n * 64 + j0) = o1;
    }
}

// ---------------------------------------------------------------------------
// CSR build: histogram -> scan -> scatter (+ dst array)
// ---------------------------------------------------------------------------
__global__ void csr_hist(const int* __restrict__ ei, int* __restrict__ cnt)
{
    int e = blockIdx.x * 256 + threadIdx.x;
    if (e >= E_EDGES) return;
    atomicAdd(&cnt[ei[E_EDGES + e]], 1);
}

__global__ void csr_scan1(const int* __restrict__ cnt, int* __restrict__ offs,
                          int* __restrict__ bsum)
{
    __shared__ int tmp[256];
    int t = threadIdx.x;
    int i = blockIdx.x * 256 + t;
    int v = (i < N_NODES) ? cnt[i] + 1 : 0;
    tmp[t] = v; __syncthreads();
#pragma unroll
    for (int o = 1; o < 256; o <<= 1) {
        int a = (t >= o) ? tmp[t - o] : 0;
        __syncthreads();
        tmp[t] += a;
        __syncthreads();
    }
    if (i < N_NODES) offs[i] = tmp[t] - v;
    if (t == 255) bsum[blockIdx.x] = tmp[255];
}

__global__ void csr_scan2(int* __restrict__ bsum)
{
    __shared__ int tmp[512];
    int t = threadIdx.x;
    int v = (t < NSCAN_BLK) ? bsum[t] : 0;
    tmp[t] = v; __syncthreads();
#pragma unroll
    for (int o = 1; o < 512; o <<= 1) {
        int a = (t >= o) ? tmp[t - o] : 0;
        __syncthreads();
        tmp[t] += a;
        __syncthreads();
    }
    if (t < NSCAN_BLK) bsum[t] = tmp[t] - v;
}

__global__ void csr_scan3(int* __restrict__ offs, const int* __restrict__ bsum,
                          int* __restrict__ cursor)
{
    int i = blockIdx.x * 256 + threadIdx.x;
    if (i < N_NODES) {
        int v = offs[i] + bsum[blockIdx.x];
        offs[i] = v;
        cursor[i] = v;
    }
    if (i == 0) offs[N_NODES] = E2;
}

__global__ void csr_scatter(const int* __restrict__ ei, int* __restrict__ cursor,
                            int* __restrict__ csr, int* __restrict__ csrd)
{
    int e = blockIdx.x * 256 + threadIdx.x;
    if (e >= E2) return;
    int d, tag;
    if (e < E_EDGES) { int s = ei[e]; d = ei[E_EDGES + e]; tag = s; }
    else             { d = e - E_EDGES; tag = d | SELF_FLAG; }
    int pos = atomicAdd(&cursor[d], 1);
    csr[pos] = tag;
    csrd[pos] = d;
}

// ---------------------------------------------------------------------------
// Fused GAT aggregate: wave per dst node; 4 edge-slots x 16 feature-lanes.
// Single pass (no segment-max; logits O(1)). bf16 gather, fp32 acc, bf16 out.
// ---------------------------------------------------------------------------
template<int ELU>
__global__ void gat_aggregate4(const int* __restrict__ offs, const int* __restrict__ csr,
                               const float* __restrict__ es, const float* __restrict__ ed,
                               const bfu* __restrict__ hsrcB, const float* __restrict__ bias,
                               bfu* __restrict__ outB)
{
    int n = blockIdx.x * 4 + (threadIdx.x >> 6);
    int lane = threadIdx.x & 63;
    if (n >= N_NODES) return;
    int g  = lane >> 4;        // edge slot 0..3
    int fl = lane & 15;        // feature chunk: features fl*4 .. fl*4+3
    int h  = fl >> 1;          // head
    int beg = offs[n], end = offs[n + 1];
    float edv = ed[n * NH + h];
    float den = 0.f;
    float4 acc = make_float4(0.f, 0.f, 0.f, 0.f);
    for (int p = beg + g; p < end; p += 4) {
        int s = csr[p] & SRC_MASK;
        float l = lrelu(es[s * NH + h] + edv);
        float ex = __expf(l);
        den += ex;
        ushort4 rb = *(const ushort4*)(hsrcB + (size_t)s * HD + fl * 4);
        acc.x = fmaf(bf2f(rb.x), ex, acc.x);
        acc.y = fmaf(bf2f(rb.y), ex, acc.y);
        acc.z = fmaf(bf2f(rb.z), ex, acc.z);
        acc.w = fmaf(bf2f(rb.w), ex, acc.w);
    }
#pragma unroll
    for (int o = 16; o <= 32; o <<= 1) {
        den   += __shfl_xor(den,   o, 64);
        acc.x += __shfl_xor(acc.x, o, 64);
        acc.y += __shfl_xor(acc.y, o, 64);
        acc.z += __shfl_xor(acc.z, o, 64);
        acc.w += __shfl_xor(acc.w, o, 64);
    }
    if (g == 0) {
        float inv = 1.f / (den + 1e-16f);
        float4 bv = *(const float4*)(bias + fl * 4);
        float v0 = acc.x * inv + bv.x;
        float v1 = acc.y * inv + bv.y;
        float v2 = acc.z * inv + bv.z;
        float v3 = acc.w * inv + bv.w;
        if (ELU) {
            v0 = v0 > 0.f ? v0 : (__expf(v0) - 1.f);
            v1 = v1 > 0.f ? v1 : (__expf(v1) - 1.f);
            v2 = v2 > 0.f ? v2 : (__expf(v2) - 1.f);
            v3 = v3 > 0.f ? v3 : (__expf(v3) - 1.f);
        }
        ushort4 ov;
        ov.x = f2bf(v0); ov.y = f2bf(v1); ov.z = f2bf(v2); ov.w = f2bf(v3);
        *(ushort4*)(outB + (size_t)n * HD + fl * 4) = ov;
    }
}

// ---------------------------------------------------------------------------
// node attention, tiled: 64 nodes/block (bf16 H) -> packed float2 alphas
// ---------------------------------------------------------------------------
__global__ __launch_bounds__(256)
void node_att_tile(const bfu* __restrict__ H, const float* __restrict__ w1,
                   const float* __restrict__ b1, const float* __restrict__ w2,
                   const float* __restrict__ b2, float2* __restrict__ al2)
{
    __shared__ float w1s[64 * 32];
    __shared__ float w2s[64];
    __shared__ float rows[64 * 65];
    int t = threadIdx.x;
    int base = blockIdx.x * 64;
    {
        const float4* w1v = (const float4*)w1;
        float4* dst = (float4*)w1s;
        for (int i = t; i < 512; i += 256) dst[i] = w1v[i];
    }
    if (t < 64) w2s[t] = w2[t];
    for (int i = t; i < 64 * 8; i += 256) {
        int r = i >> 3, c = (i & 7) * 8;
        int n = base + r;
        uint4 v = make_uint4(0, 0, 0, 0);
        if (n < N_NODES) v = *(const uint4*)(H + (size_t)n * 64 + c);
        float* dp = rows + r * 65 + c;
        dp[0] = bflo(v.x); dp[1] = bfhi(v.x);
        dp[2] = bflo(v.y); dp[3] = bfhi(v.y);
        dp[4] = bflo(v.z); dp[5] = bfhi(v.z);
        dp[6] = bflo(v.w); dp[7] = bfhi(v.w);
    }
    __syncthreads();
    int tr = t >> 3;
    int tc = t & 7;
    float4 bv = *(const float4*)(b1 + tc * 4);
    float4 acc0 = bv, acc1 = bv;
    const float4* w1sv = (const float4*)w1s;
#pragma unroll 8
    for (int k = 0; k < 64; ++k) {
        float4 w = w1sv[k * 8 + tc];
        float r0 = rows[tr * 65 + k];
        float r1 = rows[(tr + 32) * 65 + k];
        acc0.x = fmaf(r0, w.x, acc0.x); acc0.y = fmaf(r0, w.y, acc0.y);
        acc0.z = fmaf(r0, w.z, acc0.z); acc0.w = fmaf(r0, w.w, acc0.w);
        acc1.x = fmaf(r1, w.x, acc1.x); acc1.y = fmaf(r1, w.y, acc1.y);
        acc1.z = fmaf(r1, w.z, acc1.z); acc1.w = fmaf(r1, w.w, acc1.w);
    }
    float z00 = 0.f, z01 = 0.f, z10 = 0.f, z11 = 0.f;
    float h0, w20, w21;
    int j0 = tc * 4;
#pragma unroll
    for (int q = 0; q < 4; ++q) {
        float a0q = q == 0 ? acc0.x : q == 1 ? acc0.y : q == 2 ? acc0.z : acc0.w;
        float a1q = q == 0 ? acc1.x : q == 1 ? acc1.y : q == 2 ? acc1.z : acc1.w;
        w20 = w2s[(j0 + q) * 2]; w21 = w2s[(j0 + q) * 2 + 1];
        h0 = fmaxf(a0q, 0.f);
        z00 = fmaf(h0, w20, z00); z01 = fmaf(h0, w21, z01);
        h0 = fmaxf(a1q, 0.f);
        z10 = fmaf(h0, w20, z10); z11 = fmaf(h0, w21, z11);
    }
#pragma unroll
    for (int o = 1; o < 8; o <<= 1) {
        z00 += __shfl_xor(z00, o, 64); z01 += __shfl_xor(z01, o, 64);
        z10 += __shfl_xor(z10, o, 64); z11 += __shfl_xor(z11, o, 64);
    }
    if (tc == 0) {
        int n0 = base + tr, n1 = base + tr + 32;
        if (n0 < N_NODES) {
            float zz0 = z00 + b2[0], zz1 = z01 + b2[1];
            float mx = fmaxf(zz0, zz1);
            float e0 = __expf(zz0 - mx), e1 = __expf(zz1 - mx);
            float ss = e0 + e1;
            al2[n0] = make_float2(e0 / ss, e1 / ss);
        }
        if (n1 < N_NODES) {
            float zz0 = z10 + b2[0], zz1 = z11 + b2[1];
            float mx = fmaxf(zz0, zz1);
            float e0 = __expf(zz0 - mx), e1 = __expf(zz1 - mx);
            float ss = e0 + e1;
            al2[n1] = make_float2(e0 / ss, e1 / ss);
        }
    }
}

// ---------------------------------------------------------------------------
// edge attention, flat over CSR: 8 lanes/edge, bf16 P1/P2 gather. NO atomics.
// ---------------------------------------------------------------------------
__global__ __launch_bounds__(256)
void edge_att_flat(const int* __restrict__ csr, const int* __restrict__ csrd,
                   const bfu* __restrict__ P1b, const bfu* __restrict__ P2b,
                   const float* __restrict__ b1, const float* __restrict__ w2,
                   const float* __restrict__ b2,
                   float* __restrict__ bc, float* __restrict__ bt)
{
    int lane = threadIdx.x & 63;
    int sg = lane >> 3, q = lane & 7;
    int p = (blockIdx.x * 4 + (threadIdx.x >> 6)) * 8 + sg;
    if (p >= E2) return;
    int sv = csr[p];
    if (sv & SELF_FLAG) return;
    int d = csrd[p];
    uint4 U1 = *(const uint4*)(P1b + (size_t)sv * 64 + q * 8);
    uint4 U2 = *(const uint4*)(P2b + (size_t)d  * 64 + q * 8);
    const float4* pb = (const float4*)(b1 + q * 8);
    const float4* pw = (const float4*)(w2 + q * 16);
    float4 c0 = pb[0], c1 = pb[1];
    float4 w0 = pw[0], w1v = pw[1], w2v = pw[2], w3v = pw[3];
    float h0 = fmaxf(bflo(U1.x) + bflo(U2.x) + c0.x, 0.f);
    float h1 = fmaxf(bfhi(U1.x) + bfhi(U2.x) + c0.y, 0.f);
    float h2 = fmaxf(bflo(U1.y) + bflo(U2.y) + c0.z, 0.f);
    float h3 = fmaxf(bfhi(U1.y) + bfhi(U2.y) + c0.w, 0.f);
    float h4 = fmaxf(bflo(U1.z) + bflo(U2.z) + c1.x, 0.f);
    float h5 = fmaxf(bfhi(U1.z) + bfhi(U2.z) + c1.y, 0.f);
    float h6 = fmaxf(bflo(U1.w) + bflo(U2.w) + c1.z, 0.f);
    float h7 = fmaxf(bfhi(U1.w) + bfhi(U2.w) + c1.w, 0.f);
    float z0 = h0 * w0.x + h1 * w0.z + h2 * w1v.x + h3 * w1v.z
             + h4 * w2v.x + h5 * w2v.z + h6 * w3v.x + h7 * w3v.z;
    float z1 = h0 * w0.y + h1 * w0.w + h2 * w1v.y + h3 * w1v.w
             + h4 * w2v.y + h5 * w2v.w + h6 * w3v.y + h7 * w3v.w;
    z0 += __shfl_xor(z0, 1, 64); z1 += __shfl_xor(z1, 1, 64);
    z0 += __shfl_xor(z0, 2, 64); z1 += __shfl_xor(z1, 2, 64);
    z0 += __shfl_xor(z0, 4, 64); z1 += __shfl_xor(z1, 4, 64);
    if (q == 0) {
        z0 += b2[0]; z1 += b2[1];
        float mx = fmaxf(z0, z1);
        float e0 = __expf(z0 - mx), e1 = __expf(z1 - mx);
        float ss = e0 + e1;
        bc[p] = e0 / ss;
        bt[p] = e1 / ss;
    }
}

// ---------------------------------------------------------------------------
// GCN: per-node degree gather (no atomics) -> dis; then per-edge norms
// ---------------------------------------------------------------------------
__global__ void gcn_deg_dis(const int* __restrict__ offs, const int* __restrict__ csr,
                            const float* __restrict__ bc, const float* __restrict__ bt,
                            float* __restrict__ disc, float* __restrict__ dist)
{
    int n = blockIdx.x * 256 + threadIdx.x;
    if (n >= N_NODES) return;
    int beg = offs[n], end = offs[n + 1];
    float dc = 0.f, dt = 0.f;
    for (int p = beg; p < end; ++p) {
        if (csr[p] & SELF_FLAG) { dc += 1.f; dt += 1.f; }
        else { dc += bc[p]; dt += bt[p]; }
    }
    disc[n] = rsqrtf(fmaxf(dc, 1e-20f));
    dist[n] = rsqrtf(fmaxf(dt, 1e-20f));
}

__global__ void gcn_norm(const int* __restrict__ csr, const int* __restrict__ csrd,
                         const float* __restrict__ disc, const float* __restrict__ dist,
                         float* __restrict__ bc, float* __restrict__ bt)
{
    int p = blockIdx.x * 256 + threadIdx.x;
    if (p >= E2) return;
    int sv = csr[p];
    int s = sv & SRC_MASK;
    int d = csrd[p];
    float wc, wt;
    if (sv & SELF_FLAG) { wc = 1.f; wt = 1.f; }
    else { wc = bc[p]; wt = bt[p]; }
    bc[p] = disc[s] * wc * disc[d];
    bt[p] = dist[s] * wt * dist[d];
}

// ---------------------------------------------------------------------------
// weight prep: Wp = gw @ rw (64x64), bp = gb @ rw + rb
// ---------------------------------------------------------------------------
__global__ void weight_prep(const float* __restrict__ gw, const float* __restrict__ gb,
                            const float* __restrict__ rw, const float* __restrict__ rb,
                            float* __restrict__ Wp, float* __restrict__ bp)
{
    __shared__ float A[4096], B[4096];
    int t = threadIdx.x;
    {
        const float4* ga = (const float4*)gw;
        const float4* rA = (const float4*)rw;
        float4* dA = (float4*)A; float4* dB = (float4*)B;
        for (int i = t; i < 1024; i += 256) { dA[i] = ga[i]; dB[i] = rA[i]; }
    }
    __syncthreads();
    for (int e = t * 16; e < t * 16 + 16; ++e) {
        int k = e >> 6, j = e & 63;
        float acc = 0.f;
#pragma unroll 8
        for (int m = 0; m < 64; ++m) acc = fmaf(A[k * 64 + m], B[m * 64 + j], acc);
        Wp[e] = acc;
    }
    if (t < 64) {
        float acc = rb[t];
#pragma unroll 8
        for (int m = 0; m < 64; ++m) acc = fmaf(gb[m], B[m * 64 + t], acc);
        bp[t] = acc;
    }
}

// ---------------------------------------------------------------------------
// FUSED GCN aggregate + graph readout. Each graph's edges are CONTIGUOUS in
// CSR position space (csr sorted by dst, batch sorted by node). GB blocks per
// graph each sum nrm*alpha*H over a slice; partials to Pc/Pt (no atomics).
// ---------------------------------------------------------------------------
__global__ __launch_bounds__(256)
void gcn_readout_fused(const int* __restrict__ offs, const int* __restrict__ csr,
                       const int* __restrict__ batch,
                       const bfu* __restrict__ HB, const float2* __restrict__ al2,
                       const float* __restrict__ nrmC, const float* __restrict__ nrmT,
                       float* __restrict__ Pc, float* __restrict__ Pt)
{
    int g = blockIdx.x / GB, b = blockIdx.x % GB;
    int t = threadIdx.x;
    int lo, hi;
    {
        int l = 0, r = N_NODES;
        while (l < r) { int m = (l + r) >> 1; if (batch[m] < g) l = m + 1; else r = m; }
        lo = l;
        r = N_NODES;
        while (l < r) { int m = (l + r) >> 1; if (batch[m] < g + 1) l = m + 1; else r = m; }
        hi = l;
    }
    int pbeg = offs[lo], pend = offs[hi];      // offs[N_NODES] = E2
    int total = pend - pbeg;
    int chunk = (total + GB - 1) / GB;
    int start = pbeg + b * chunk;
    int end = start + chunk;
    if (end > pend) end = pend;
    if (start > pend) start = pend;
    int slot = t >> 4, fl = t & 15;
    float4 a1 = make_float4(0.f, 0.f, 0.f, 0.f);
    float4 a2 = make_float4(0.f, 0.f, 0.f, 0.f);
    int p = start + slot;
    for (; p + 16 < end; p += 32) {
        int s0 = csr[p] & SRC_MASK;
        int s1 = csr[p + 16] & SRC_MASK;
        float2 al0 = al2[s0], al1 = al2[s1];
        float wc0 = nrmC[p] * al0.x,      wt0 = nrmT[p] * al0.y;
        float wc1 = nrmC[p + 16] * al1.x, wt1 = nrmT[p + 16] * al1.y;
        ushort4 r0 = *(const ushort4*)(HB + (size_t)s0 * HD + fl * 4);
        ushort4 r1 = *(const ushort4*)(HB + (size_t)s1 * HD + fl * 4);
        float f00 = bf2f(r0.x), f01 = bf2f(r0.y), f02 = bf2f(r0.z), f03 = bf2f(r0.w);
        float f10 = bf2f(r1.x), f11 = bf2f(r1.y), f12 = bf2f(r1.z), f13 = bf2f(r1.w);
        a1.x = fmaf(f00, wc0, fmaf(f10, wc1, a1.x));
        a1.y = fmaf(f01, wc0, fmaf(f11, wc1, a1.y));
        a1.z = fmaf(f02, wc0, fmaf(f12, wc1, a1.z));
        a1.w = fmaf(f03, wc0, fmaf(f13, wc1, a1.w));
        a2.x = fmaf(f00, wt0, fmaf(f10, wt1, a2.x));
        a2.y = fmaf(f01, wt0, fmaf(f11, wt1, a2.y));
        a2.z = fmaf(f02, wt0, fmaf(f12, wt1, a2.z));
        a2.w = fmaf(f03, wt0, fmaf(f13, wt1, a2.w));
    }
    if (p < end) {
        int s0 = csr[p] & SRC_MASK;
        float2 al0 = al2[s0];
        float wc0 = nrmC[p] * al0.x, wt0 = nrmT[p] * al0.y;
        ushort4 r0 = *(const ushort4*)(HB + (size_t)s0 * HD + fl * 4);
        float f00 = bf2f(r0.x), f01 = bf2f(r0.y), f02 = bf2f(r0.z), f03 = bf2f(r0.w);
        a1.x = fmaf(f00, wc0, a1.x); a1.y = fmaf(f01, wc0, a1.y);
        a1.z = fmaf(f02, wc0, a1.z); a1.w = fmaf(f03, wc0, a1.w);
        a2.x = fmaf(f00, wt0, a2.x); a2.y = fmaf(f01, wt0, a2.y);
        a2.z = fmaf(f02, wt0, a2.z); a2.w = fmaf(f03, wt0, a2.w);
    }
    __shared__ float redc[16 * 64], redt[16 * 64];
    *(float4*)(redc + slot * 64 + fl * 4) = a1;
    *(float4*)(redt + slot * 64 + fl * 4) = a2;
    __syncthreads();
    if (t < 64) {
        float sc = 0.f, st = 0.f;
#pragma unroll
        for (int s = 0; s < 16; ++s) { sc += redc[s * 64 + t]; st += redt[s * 64 + t]; }
        Pc[(size_t)blockIdx.x * 64 + t] = sc;
        Pt[(size_t)blockIdx.x * 64 + t] = st;
    }
}

// ---------------------------------------------------------------------------
// final heads: one 64-thread block per graph. Reduces GB partials, applies
// commuted weights (Wcp = gc_w@rc_w etc.), then the three classifier MLPs.
// ---------------------------------------------------------------------------
__global__ __launch_bounds__(64)
void head_final(const float* __restrict__ Pc, const float* __restrict__ Pt,
                const int* __restrict__ batch,
                const float* __restrict__ Wcp, const float* __restrict__ bcp,
                const float* __restrict__ Wtp, const float* __restrict__ btp,
                const float* __restrict__ cc_w1, const float* __restrict__ cc_b1,
                const float* __restrict__ cc_w2, const float* __restrict__ cc_b2,
                const float* __restrict__ ct_w1, const float* __restrict__ ct_b1,
                const float* __restrict__ ct_w2, const float* __restrict__ ct_b2,
                const float* __restrict__ cm_w1, const float* __restrict__ cm_b1,
                const float* __restrict__ cm_w2, const float* __restrict__ cm_b2,
                float* __restrict__ out)
{
    int g = blockIdx.x;
    int t = threadIdx.x;
    __shared__ float scl[64], stl[64], hgc[64], hgt[64], hid[64];
    float sc = 0.f, st = 0.f;
#pragma unroll
    for (int b = 0; b < GB; ++b) {
        sc += Pc[(size_t)(g * GB + b) * 64 + t];
        st += Pt[(size_t)(g * GB + b) * 64 + t];
    }
    scl[t] = sc; stl[t] = st;
    int lo, hi;
    {
        int l = 0, r = N_NODES;
        while (l < r) { int m = (l + r) >> 1; if (batch[m] < g) l = m + 1; else r = m; }
        lo = l;
        r = N_NODES;
        while (l < r) { int m = (l + r) >> 1; if (batch[m] < g + 1) l = m + 1; else r = m; }
        hi = l;
    }
    float c = (float)(hi - lo);
    __syncthreads();
    {
        float a = c * bcp[t], bb = c * btp[t];
#pragma unroll 8
        for (int k = 0; k < 64; ++k) {
            a  = fmaf(scl[k], Wcp[k * 64 + t], a);
            bb = fmaf(stl[k], Wtp[k * 64 + t], bb);
        }
        hgc[t] = a; hgt[t] = bb;
        out[3840 + g * 64 + t]  = a;
        out[12032 + g * 64 + t] = bb;
    }
    __syncthreads();
    if (t < 32) {
        float a = cc_b1[t];
#pragma unroll 8
        for (int k = 0; k < 64; ++k) a = fmaf(hgc[k], cc_w1[k * 32 + t], a);
        hid[t] = fmaxf(a, 0.f);
    }
    __syncthreads();
    if (t < NC) {
        float a = cc_b2[t];
#pragma unroll
        for (int k = 0; k < 32; ++k) a = fmaf(hid[k], cc_w2[k * NC + t], a);
        out[g * NC + t] = a;
    }
    __syncthreads();
    if (t < 32) {
        float a = ct_b1[t];
#pragma unroll 8
        for (int k = 0; k < 64; ++k) a = fmaf(hgt[k], ct_w1[k * 32 + t], a);
        hid[t] = fmaxf(a, 0.f);
    }
    __syncthreads();
    if (t < NC) {
        float a = ct_b2[t];
#pragma unroll
        for (int k = 0; k < 32; ++k) a = fmaf(hid[k], ct_w2[k * NC + t], a);
        out[1280 + g * NC + t] = a;
    }
    __syncthreads();
    {
        float a = cm_b1[t];
#pragma unroll 8
        for (int k = 0; k < 64; ++k) {
            a = fmaf(hgc[k], cm_w1[k * 64 + t], a);
            a = fmaf(hgt[k], cm_w1[(64 + k) * 64 + t], a);
        }
        hid[t] = fmaxf(a, 0.f);
    }
    __syncthreads();
    if (t < NC) {
        float a = cm_b2[t];
#pragma unroll 8
        for (int k = 0; k < 64; ++k) a = fmaf(hid[k], cm_w2[k * NC + t], a);
        out[2560 + g * NC + t] = a;
    }
}

// ---------------------------------------------------------------------------
extern "C" void kernel_launch(void* const* d_in, const int* in_sizes, int n_in,
                              void* d_out, int out_size, void* d_ws, size_t ws_size,
                              hipStream_t stream)
{
    const float* x     = (const float*)d_in[0];
    const int*   ei    = (const int*)d_in[1];
    const int*   batch = (const int*)d_in[2];
    const float* W1    = (const float*)d_in[3];
    const float* as1   = (const float*)d_in[4];
    const float* ad1   = (const float*)d_in[5];
    const float* b1    = (const float*)d_in[6];
    const float* W2    = (const float*)d_in[7];
    const float* as2   = (const float*)d_in[8];
    const float* ad2   = (const float*)d_in[9];
    const float* b2    = (const float*)d_in[10];
    const float* na_w1 = (const float*)d_in[11];
    const float* na_b1 = (const float*)d_in[12];
    const float* na_w2 = (const float*)d_in[13];
    const float* na_b2 = (const float*)d_in[14];
    const float* ea_w1 = (const float*)d_in[15];
    const float* ea_b1 = (const float*)d_in[16];
    const float* ea_w2 = (const float*)d_in[17];
    const float* ea_b2 = (const float*)d_in[18];
    const float* gc_w  = (const float*)d_in[19];
    const float* gc_b  = (const float*)d_in[20];
    const float* gt_w  = (const float*)d_in[21];
    const float* gt_b  = (const float*)d_in[22];
    const float* rc_w  = (const float*)d_in[23];
    const float* rc_b  = (const float*)d_in[24];
    const float* rt_w  = (const float*)d_in[25];
    const float* rt_b  = (const float*)d_in[26];
    const float* cc_w1 = (const float*)d_in[27];
    const float* cc_b1 = (const float*)d_in[28];
    const float* cc_w2 = (const float*)d_in[29];
    const float* cc_b2 = (const float*)d_in[30];
    const float* ct_w1 = (const float*)d_in[31];
    const float* ct_b1 = (const float*)d_in[32];
    const float* ct_w2 = (const float*)d_in[33];
    const float* ct_b2 = (const float*)d_in[34];
    const float* cm_w1 = (const float*)d_in[35];
    const float* cm_b1 = (const float*)d_in[36];
    const float* cm_w2 = (const float*)d_in[37];
    const float* cm_b2 = (const float*)d_in[38];
    float* out = (float*)d_out;

    float* ws = (float*)d_ws;
    size_t o = 0;
    const size_t nf = (size_t)N_NODES * HD;
    float* es   = ws + o; o += (size_t)N_NODES * NH;
    float* ed   = ws + o; o += (size_t)N_NODES * NH;
    float2* al2 = (float2*)(ws + o); o += (size_t)N_NODES * 2;
    float* bc   = ws + o; o += E2;             // beta_c -> norm_c (in place)
    float* bt   = ws + o; o += E2;             // beta_t -> norm_t (in place)
    float* degc = ws + o; o += N_NODES;        // dis_c
    float* degt = ws + o; o += N_NODES;
    bfu* B0     = (bfu*)(ws + o); o += nf / 2; // transform/P1 table
    bfu* B1     = (bfu*)(ws + o); o += nf / 2; // P2 table
    bfu* B2     = (bfu*)(ws + o); o += nf / 2; // H table (bf16)
    bfu* BH1    = (bfu*)(ws + o); o += nf / 2; // H1 table (bf16)
    int* csr    = (int*)(ws + o); o += E2;
    int* csrd   = (int*)(ws + o); o += E2;
    int* offs   = (int*)(ws + o); o += N_NODES + 1;
    float* Pc   = ws + o; o += (size_t)NG * GB * 64;
    float* Pt   = ws + o; o += (size_t)NG * GB * 64;
    float* Wcp  = ws + o; o += 4096;
    float* Wtp  = ws + o; o += 4096;
    float* bcp  = ws + o; o += 64;
    float* btp  = ws + o; o += 64;
    // CSR-build temporaries alias buffers written later:
    int* cnt    = (int*)bc;
    int* cursor = (int*)bt;
    int* bsum   = (int*)degc;

    const int NW_BLKS = N_NODES / 4;             // 25000
    const int NT_BLKS = (N_NODES + 255) / 256;   // 391
    const int E_BLKS  = (E2 + 255) / 256;        // 3516
    const int EF_BLKS = (E2 + 31) / 32;          // 28125

    // ---------------- CSR build ----------------
    hipMemsetAsync(cnt, 0, (size_t)N_NODES * 4, stream);
    csr_hist<<<(E_EDGES + 255) / 256, 256, 0, stream>>>(ei, cnt);
    csr_scan1<<<NSCAN_BLK, 256, 0, stream>>>(cnt, offs, bsum);
    csr_scan2<<<1, 512, 0, stream>>>(bsum);
    csr_scan3<<<NSCAN_BLK, 256, 0, stream>>>(offs, bsum, cursor);
    csr_scatter<<<E_BLKS, 256, 0, stream>>>(ei, cursor, csr, csrd);

    // ---------------- GAT layer 1 ----------------
    gemm_tile<float, FIN, 1><<<NBLK64, 256, 0, stream>>>(x, W1, B0, as1, ad1, es, ed);
    gat_aggregate4<1><<<NW_BLKS, 256, 0, stream>>>(offs, csr, es, ed, B0, b1, BH1);

    // ---------------- GAT layer 2 ----------------
    gemm_tile<bfu, 64, 1><<<NBLK64, 256, 0, stream>>>(BH1, W2, B0, as2, ad2, es, ed);
    gat_aggregate4<0><<<NW_BLKS, 256, 0, stream>>>(offs, csr, es, ed, B0, b2, B2);

    // ---------------- node attention (alpha pair) ----------------
    node_att_tile<<<NBLK64, 256, 0, stream>>>(B2, na_w1, na_b1, na_w2, na_b2, al2);

    // ---------------- edge attention (P1 -> B0, P2 -> B1) -------------------
    gemm_dual<<<NBLK64, 256, 0, stream>>>(B2, ea_w1, ea_w1 + 64 * 64, B0, B1);
    edge_att_flat<<<EF_BLKS, 256, 0, stream>>>(csr, csrd, B0, B1, ea_b1, ea_w2, ea_b2, bc, bt);

    // ---------------- GCN norm (bc/bt -> per-edge norms in place) -----------
    gcn_deg_dis<<<NT_BLKS, 256, 0, stream>>>(offs, csr, bc, bt, degc, degt);
    gcn_norm<<<E_BLKS, 256, 0, stream>>>(csr, csrd, degc, degt, bc, bt);

    // ---------------- weight prep (commuted GCN+readout weights) ------------
    weight_prep<<<1, 256, 0, stream>>>(gc_w, gc_b, rc_w, rc_b, Wcp, bcp);
    weight_prep<<<1, 256, 0, stream>>>(gt_w, gt_b, rt_w, rt_b, Wtp, btp);

    // ---------------- fused GCN aggregate + readout -------------------------
    gcn_readout_fused<<<NG * GB, 256, 0, stream>>>(offs, csr, batch, B2, al2,
                                                   bc, bt, Pc, Pt);

    // ---------------- final heads -------------------------------------------
    head_final<<<NG, 64, 0, stream>>>(Pc, Pt, batch,
                                      Wcp, bcp, Wtp, btp,
                                      cc_w1, cc_b1, cc_w2, cc_b2,
                                      ct_w1, ct_b1, ct_w2, ct_b2,
                                      cm_w1, cm_b1, cm_w2, cm_b2, out);
    (void)in_sizes; (void)n_in; (void)out_size; (void)ws_size;
}